// Round 11
// baseline (729.236 us; speedup 1.0000x reference)
//
#include <hip/hip_runtime.h>
#include <hip/hip_bf16.h>

#define H 128
#define NFEAT 10
#define EFEAT 10

typedef __attribute__((ext_vector_type(8))) short bf16x8;
typedef __attribute__((ext_vector_type(4))) float f32x4;

__device__ __forceinline__ float bflo(unsigned v) { return __uint_as_float(v << 16); }
__device__ __forceinline__ float bfhi(unsigned v) { return __uint_as_float(v & 0xffff0000u); }
__device__ __forceinline__ unsigned bfpack(float a, float b) {
    __hip_bfloat16 h0 = __float2bfloat16(a), h1 = __float2bfloat16(b);
    return (unsigned)(*(unsigned short*)&h0) | ((unsigned)(*(unsigned short*)&h1) << 16);
}

// ---------------- CSR build ----------------
__global__ __launch_bounds__(256) void k_degree(const int* __restrict__ col,
                                                int* __restrict__ deg, int E, int N) {
    int i = blockIdx.x * blockDim.x + threadIdx.x;
    int E2 = E + N;
    if (i < E2) {
        int d = (i < E) ? col[i] : (i - E);
        atomicAdd(&deg[d], 1);
    }
}

__global__ __launch_bounds__(1024) void k_scan(const int* __restrict__ deg,
                                               int* __restrict__ offs,
                                               int* __restrict__ cursor, int N) {
    __shared__ int ps[1024];
    int t = threadIdx.x;
    int chunk = (N + 1023) / 1024;
    int begin = t * chunk;
    int end = begin + chunk; if (end > N) end = N;
    int s = 0;
    for (int i = begin; i < end; i++) s += deg[i];
    if (begin >= N) s = 0;
    ps[t] = s;
    __syncthreads();
    for (int off = 1; off < 1024; off <<= 1) {
        int v = (t >= off) ? ps[t - off] : 0;
        __syncthreads();
        ps[t] += v;
        __syncthreads();
    }
    int run = (t == 0) ? 0 : ps[t - 1];
    if (begin < N) {
        for (int i = begin; i < end; i++) {
            offs[i] = run;
            cursor[i] = run;
            run += deg[i];
        }
    }
    if (t == 1023) offs[N] = ps[1023];
}

__global__ __launch_bounds__(256) void k_scatter(const int* __restrict__ rowp,
                                                 const int* __restrict__ colp,
                                                 int* __restrict__ cursor,
                                                 int* __restrict__ srcs, int E, int N) {
    int i = blockIdx.x * blockDim.x + threadIdx.x;
    if (i < E + N) {
        int s, d;
        if (i < E) { s = rowp[i]; d = colp[i]; }
        else       { s = i - E;  d = i - E; }
        int pos = atomicAdd(&cursor[d], 1);
        srcs[pos] = s;
    }
}

// ---------------- Node encoder: 1 wave/node, lane = 2 features ----------------
__global__ __launch_bounds__(256) void k_node_enc(const float* __restrict__ x,
                                                  const float* __restrict__ wm,
                                                  const float* __restrict__ b,
                                                  const float* __restrict__ g,
                                                  const float* __restrict__ beta,
                                                  __hip_bfloat16* __restrict__ h, int N) {
    int t = threadIdx.x;
    int w = t >> 6, l = t & 63;
    int n = blockIdx.x * 4 + w;
    if (n >= N) return;
    float xs[NFEAT];
#pragma unroll
    for (int k = 0; k < NFEAT; k++) xs[k] = x[(size_t)n * NFEAT + k];
    float a0 = b[2 * l], a1 = b[2 * l + 1];
#pragma unroll
    for (int k = 0; k < NFEAT; k++) {
        float2 wv = *(const float2*)&wm[k * H + 2 * l];
        a0 += xs[k] * wv.x;
        a1 += xs[k] * wv.y;
    }
    float p = a0 + a1;
#pragma unroll
    for (int s = 1; s < 64; s <<= 1) p += __shfl_xor(p, s, 64);
    float mean = p * (1.0f / H);
    float d0 = a0 - mean, d1 = a1 - mean;
    float q = d0 * d0 + d1 * d1;
#pragma unroll
    for (int s = 1; s < 64; s <<= 1) q += __shfl_xor(q, s, 64);
    float rstd = rsqrtf(q * (1.0f / H) + 1e-5f);
    float y0 = fmaxf(d0 * rstd * g[2 * l] + beta[2 * l], 0.0f);
    float y1 = fmaxf(d1 * rstd * g[2 * l + 1] + beta[2 * l + 1], 0.0f);
    *(unsigned*)&h[(size_t)n * H + 2 * l] = bfpack(y0, y1);
}

// ---------------- GAT stage 1: MFMA xp = h@w, fused scores ----------------
__global__ __launch_bounds__(256, 2) void k_gat_xp_mfma(
        const __hip_bfloat16* __restrict__ h_bf,
        const __hip_bfloat16* __restrict__ wT,
        const float* __restrict__ asrc,
        const float* __restrict__ adst,
        __hip_bfloat16* __restrict__ xp_bf,
        float* __restrict__ a_s, float* __restrict__ a_d,
        int heads, int N) {
    __shared__ __hip_bfloat16 Ws[128 * 136];
    __shared__ __hip_bfloat16 As[64 * 136];
    int t = threadIdx.x;
    int n0 = blockIdx.x * 64;

#pragma unroll
    for (int it = 0; it < 2; it++) {
        int idx = it * 256 + t;
        int row = idx >> 2, seg = idx & 3;
        const uint4* src = (const uint4*)(wT + row * 128 + seg * 32);
        uint4 v0 = src[0], v1 = src[1], v2 = src[2], v3 = src[3];
        uint4* dst = (uint4*)&Ws[row * 136 + seg * 32];
        dst[0] = v0; dst[1] = v1; dst[2] = v2; dst[3] = v3;
    }
    {
        int row = t >> 2, seg = t & 3;
        int n = n0 + row; if (n >= N) n = N - 1;
        const uint4* src = (const uint4*)(h_bf + (size_t)n * 128 + seg * 32);
        uint4 v0 = src[0], v1 = src[1], v2 = src[2], v3 = src[3];
        uint4* dst = (uint4*)&As[row * 136 + seg * 32];
        dst[0] = v0; dst[1] = v1; dst[2] = v2; dst[3] = v3;
    }
    __syncthreads();

    int w = t >> 6, l = t & 63, ln15 = l & 15, quad = l >> 4, q8 = quad * 8;
    f32x4 acc[8] = {};
#pragma unroll
    for (int k = 0; k < 128; k += 32) {
        bf16x8 af = *(const bf16x8*)&As[(w * 16 + ln15) * 136 + k + q8];
#pragma unroll
        for (int i = 0; i < 8; i++) {
            bf16x8 bfr = *(const bf16x8*)&Ws[(i * 16 + ln15) * 136 + k + q8];
            acc[i] = __builtin_amdgcn_mfma_f32_16x16x32_bf16(af, bfr, acc[i], 0, 0, 0);
        }
    }

    if (heads == 8) {
#pragma unroll
        for (int i = 0; i < 8; i++) {
            float av = asrc[i * 16 + ln15], dvv = adst[i * 16 + ln15];
            float ps[4], pd[4];
#pragma unroll
            for (int r = 0; r < 4; r++) { ps[r] = acc[i][r] * av; pd[r] = acc[i][r] * dvv; }
#pragma unroll
            for (int s = 1; s < 16; s <<= 1) {
#pragma unroll
                for (int r = 0; r < 4; r++) {
                    ps[r] += __shfl_xor(ps[r], s, 64);
                    pd[r] += __shfl_xor(pd[r], s, 64);
                }
            }
            if (ln15 == 0) {
#pragma unroll
                for (int r = 0; r < 4; r++) {
                    int n = n0 + w * 16 + quad * 4 + r;
                    if (n < N) { a_s[(size_t)n * 8 + i] = ps[r]; a_d[(size_t)n * 8 + i] = pd[r]; }
                }
            }
        }
    } else {
        float ps[4] = {0, 0, 0, 0}, pd[4] = {0, 0, 0, 0};
#pragma unroll
        for (int i = 0; i < 8; i++) {
            float av = asrc[i * 16 + ln15], dvv = adst[i * 16 + ln15];
#pragma unroll
            for (int r = 0; r < 4; r++) { ps[r] += acc[i][r] * av; pd[r] += acc[i][r] * dvv; }
        }
#pragma unroll
        for (int s = 1; s < 16; s <<= 1) {
#pragma unroll
            for (int r = 0; r < 4; r++) {
                ps[r] += __shfl_xor(ps[r], s, 64);
                pd[r] += __shfl_xor(pd[r], s, 64);
            }
        }
        if (ln15 == 0) {
#pragma unroll
            for (int r = 0; r < 4; r++) {
                int n = n0 + w * 16 + quad * 4 + r;
                if (n < N) { a_s[n] = ps[r]; a_d[n] = pd[r]; }
            }
        }
    }

#pragma unroll
    for (int i = 0; i < 8; i++) {
#pragma unroll
        for (int r = 0; r < 4; r++) {
            int n = n0 + w * 16 + quad * 4 + r;
            if (n < N) xp_bf[(size_t)n * 128 + i * 16 + ln15] = __float2bfloat16(acc[i][r]);
        }
    }
}

// ---------------- GAT stage 2: 1 wave/node, 8x pipelined gather ----------------
__global__ __launch_bounds__(256) void k_gat_agg(const __hip_bfloat16* __restrict__ xp,
                                                 const float* __restrict__ a_s,
                                                 const float* __restrict__ a_d,
                                                 const int* __restrict__ offs,
                                                 const int* __restrict__ srcs,
                                                 const float* __restrict__ bias,
                                                 const float* __restrict__ g,
                                                 const float* __restrict__ b,
                                                 __hip_bfloat16* __restrict__ hout,
                                                 int heads, int N) {
    int t = threadIdx.x;
    int w = t >> 6, l = t & 63;
    int n = blockIdx.x * 4 + w;
    if (n >= N) return;
    int head = (heads == 8) ? (l >> 3) : 0;
    float adv = a_d[(size_t)n * heads + head];
    int s0 = offs[n], s1 = offs[n + 1];
    float acc0 = 0.0f, acc1 = 0.0f, den = 0.0f;
    int j = s0;
    for (; j + 8 <= s1; j += 8) {
        int s_[8];
#pragma unroll
        for (int u = 0; u < 8; u++) s_[u] = srcs[j + u];
        float e_[8]; unsigned v_[8];
#pragma unroll
        for (int u = 0; u < 8; u++) {
            e_[u] = a_s[(size_t)s_[u] * heads + head];
            v_[u] = *(const unsigned*)&xp[(size_t)s_[u] * H + 2 * l];
        }
#pragma unroll
        for (int u = 0; u < 8; u++) {
            float e = e_[u] + adv;
            e = (e >= 0.0f) ? e : 0.2f * e;
            float ex = __expf(e);
            den += ex;
            acc0 += ex * bflo(v_[u]);
            acc1 += ex * bfhi(v_[u]);
        }
    }
    for (; j < s1; j++) {
        int s = srcs[j];
        float e = a_s[(size_t)s * heads + head] + adv;
        e = (e >= 0.0f) ? e : 0.2f * e;
        float ex = __expf(e);
        den += ex;
        unsigned v = *(const unsigned*)&xp[(size_t)s * H + 2 * l];
        acc0 += ex * bflo(v);
        acc1 += ex * bfhi(v);
    }
    float inv = 1.0f / den;
    float v0 = acc0 * inv + bias[2 * l];
    float v1 = acc1 * inv + bias[2 * l + 1];
    float p = v0 + v1;
#pragma unroll
    for (int s = 1; s < 64; s <<= 1) p += __shfl_xor(p, s, 64);
    float mean = p * (1.0f / H);
    float d0 = v0 - mean, d1 = v1 - mean;
    float q = d0 * d0 + d1 * d1;
#pragma unroll
    for (int s = 1; s < 64; s <<= 1) q += __shfl_xor(q, s, 64);
    float rstd = rsqrtf(q * (1.0f / H) + 1e-5f);
    float y0 = fmaxf(d0 * rstd * g[2 * l] + b[2 * l], 0.0f);
    float y1 = fmaxf(d1 * rstd * g[2 * l + 1] + b[2 * l + 1], 0.0f);
    *(unsigned*)&hout[(size_t)n * H + 2 * l] = bfpack(y0, y1);
}

// ---------------- weight prep: fragment-swizzled bf16 ----------------
__global__ __launch_bounds__(256) void k_wprep(const float* __restrict__ gate_w,
                                               const float* __restrict__ c1_w,
                                               const float* __restrict__ c2_w,
                                               const float* __restrict__ gatA_w,
                                               const float* __restrict__ gatB_w,
                                               const float* __restrict__ ee_w,
                                               __hip_bfloat16* __restrict__ gate_sw,
                                               __hip_bfloat16* __restrict__ c1_sw,
                                               __hip_bfloat16* __restrict__ c2_sw,
                                               __hip_bfloat16* __restrict__ wT3,
                                               __hip_bfloat16* __restrict__ ee_sw) {
    int i = blockIdx.x * blockDim.x + threadIdx.x;
    if (i < 49152) {                       // gate
        int j = i & 7, lane = (i >> 3) & 63, rest = i >> 9;
        int nt = rest & 7, kc = rest >> 3;
        int n = nt * 16 + (lane & 15);
        int k = kc * 32 + (lane >> 4) * 8 + j;
        gate_sw[i] = __float2bfloat16(gate_w[k * 128 + n]);
    } else if (i < 81920) {                // c1
        int m = i - 49152;
        int j = m & 7, lane = (m >> 3) & 63, rest = m >> 9;
        int nt = rest & 7, kc = rest >> 3;
        int n = nt * 16 + (lane & 15);
        int k = kc * 32 + (lane >> 4) * 8 + j;
        c1_sw[m] = __float2bfloat16(c1_w[k * 128 + n]);
    } else if (i < 90112) {                // c2
        int m = i - 81920;
        int j = m & 7, lane = (m >> 3) & 63, rest = m >> 9;
        int nt = rest & 3, kc = rest >> 2;
        int n = nt * 16 + (lane & 15);
        int k = kc * 32 + (lane >> 4) * 8 + j;
        c2_sw[m] = __float2bfloat16(c2_w[k * 64 + n]);
    } else if (i < 139264) {               // gatA[0], gatA[1], gatB
        int m = i - 90112;
        int mat = m / 16384, r = m % 16384;
        int n = r / 128, k = r % 128;
        const float* src = (mat < 2) ? (gatA_w + (size_t)mat * 16384) : gatB_w;
        wT3[m] = __float2bfloat16(src[k * 128 + n]);
    } else if (i < 143360) {               // ee_sw (K padded to 32)
        int m = i - 139264;
        int j = m & 7, lane = (m >> 3) & 63, nt = (m >> 9) & 7;
        int n = nt * 16 + (lane & 15);
        int k = (lane >> 4) * 8 + j;
        ee_sw[m] = (k < EFEAT) ? __float2bfloat16(ee_w[k * 128 + n]) : __float2bfloat16(0.0f);
    }
}

// ---------------- Edge classifier: single-pass 4-GEMM MFMA MLP ----------------
// 64 edges/block, 4 waves; wave owns 16 edges + all N-tiles. No __syncthreads.
// Depth-4 B-frag FIFO; inline A-streams. __launch_bounds__(256,3): VGPR cap
// ~168 (NO spill — the (256,4)=64-VGPR cap was causing 37-70 MB scratch
// traffic), 3 blocks/CU (LDS 33.8K x 3 = 101 KB).
__global__ __launch_bounds__(256, 3) void k_edge_cls_mfma(
        const __hip_bfloat16* __restrict__ h_bf,
        const int* __restrict__ rowp, const int* __restrict__ colp,
        const float* __restrict__ eattr,
        const __hip_bfloat16* __restrict__ ee_sw, const float* __restrict__ ee_b,
        const float* __restrict__ ee_g, const float* __restrict__ ee_beta,
        const __hip_bfloat16* __restrict__ gate_sw, const float* __restrict__ gate_b,
        const __hip_bfloat16* __restrict__ c1_sw, const float* __restrict__ c1_b,
        const float* __restrict__ cl1_g, const float* __restrict__ cl1_b,
        const __hip_bfloat16* __restrict__ c2_sw, const float* __restrict__ c2_b,
        const float* __restrict__ cl2_g, const float* __restrict__ cl2_b,
        const float* __restrict__ c3_w, const float* __restrict__ c3_b,
        float* __restrict__ out, int E) {
    __shared__ __align__(16) __hip_bfloat16 Bs[4 * 16 * 264];
    int t = threadIdx.x;
    int w = t >> 6, l = t & 63;
    int ln15 = l & 15, quad = l >> 4, q8 = quad * 8;
    int e0 = blockIdx.x * 64;
    int rbase = w * 16;
    __hip_bfloat16* B = Bs + w * (16 * 264);

    // fragment-row edge + node pointers (row = ln15)
    int eF = e0 + rbase + ln15; if (eF >= E) eF = E - 1;
    const __hip_bfloat16* rowS = h_bf + (size_t)rowp[eF] * 128;
    const __hip_bfloat16* rowD = h_bf + (size_t)colp[eF] * 128;

    // ---- GEMM0: Ef = relu(LN(ea @ ee_w + ee_b)) -> B[:,0:128] ----
    {
        bf16x8 afe;
#pragma unroll
        for (int j = 0; j < 8; j++) {
            int k = q8 + j;
            float v = (k < EFEAT) ? eattr[(size_t)eF * EFEAT + k] : 0.0f;
            __hip_bfloat16 hv = __float2bfloat16(v);
            afe[j] = *(short*)&hv;
        }
        f32x4 acc[8] = {};
#pragma unroll
        for (int i = 0; i < 8; i++) {
            bf16x8 bfr = *(const bf16x8*)(ee_sw + ((size_t)i * 64 + l) * 8);
            acc[i] = __builtin_amdgcn_mfma_f32_16x16x32_bf16(afe, bfr, acc[i], 0, 0, 0);
        }
#pragma unroll
        for (int i = 0; i < 8; i++) {
            float cb = ee_b[i * 16 + ln15];
#pragma unroll
            for (int r = 0; r < 4; r++) acc[i][r] += cb;
        }
        float mean[4], rstd[4];
#pragma unroll
        for (int r = 0; r < 4; r++) {
            float p = 0.0f;
#pragma unroll
            for (int i = 0; i < 8; i++) p += acc[i][r];
            p += __shfl_xor(p, 1, 64); p += __shfl_xor(p, 2, 64);
            p += __shfl_xor(p, 4, 64); p += __shfl_xor(p, 8, 64);
            mean[r] = p * (1.0f / 128.0f);
        }
#pragma unroll
        for (int r = 0; r < 4; r++) {
            float q = 0.0f;
#pragma unroll
            for (int i = 0; i < 8; i++) { float d = acc[i][r] - mean[r]; q += d * d; }
            q += __shfl_xor(q, 1, 64); q += __shfl_xor(q, 2, 64);
            q += __shfl_xor(q, 4, 64); q += __shfl_xor(q, 8, 64);
            rstd[r] = rsqrtf(q * (1.0f / 128.0f) + 1e-5f);
        }
#pragma unroll
        for (int i = 0; i < 8; i++) {
            int cn = i * 16 + ln15;
            float g1 = ee_g[cn], b1 = ee_beta[cn];
#pragma unroll
            for (int r = 0; r < 4; r++) {
                int qr = quad * 4 + r;
                float y = fmaxf((acc[i][r] - mean[r]) * rstd[r] * g1 + b1, 0.0f);
                B[qr * 264 + cn] = __float2bfloat16(y);
            }
        }
    }

    // ---- GEMM1: gate = sigmoid([S|D|Ef]@gate_w + b); B <- [S+g*Ef | D+g*Ef] ----
    {
        f32x4 acc[8] = {};
        bf16x8 fifo[4];
#pragma unroll
        for (int s = 0; s < 4; s++)
            fifo[s] = *(const bf16x8*)(gate_sw + ((size_t)s * 64 + l) * 8);
        bf16x8 acur = *(const bf16x8*)(rowS + q8);
        bf16x8 anx;
#pragma unroll
        for (int s = 0; s < 96; s++) {
            int kc = s >> 3, i = s & 7;
            if (i == 0 && kc < 11) {
                int k1 = kc + 1;
                if (k1 < 4)      anx = *(const bf16x8*)(rowS + k1 * 32 + q8);
                else if (k1 < 8) anx = *(const bf16x8*)(rowD + (k1 - 4) * 32 + q8);
                else             anx = *(const bf16x8*)&B[ln15 * 264 + (k1 - 8) * 32 + q8];
            }
            bf16x8 bcur = fifo[s & 3];
            if (s + 4 < 96)
                fifo[s & 3] = *(const bf16x8*)(gate_sw + ((size_t)(s + 4) * 64 + l) * 8);
            acc[i] = __builtin_amdgcn_mfma_f32_16x16x32_bf16(acur, bcur, acc[i], 0, 0, 0);
            if (i == 7) acur = anx;
        }
#pragma unroll
        for (int r = 0; r < 4; r++) {
            int qr = quad * 4 + r;
            int er = e0 + rbase + qr; if (er >= E) er = E - 1;
            const __hip_bfloat16* rS = h_bf + (size_t)rowp[er] * 128;
            const __hip_bfloat16* rD = h_bf + (size_t)colp[er] * 128;
#pragma unroll
            for (int i = 0; i < 8; i++) {
                int cn = i * 16 + ln15;
                float gt = 1.0f / (1.0f + __expf(-(acc[i][r] + gate_b[cn])));
                float ef = __bfloat162float(B[qr * 264 + cn]);   // Ef (read before overwrite)
                float s  = __bfloat162float(rS[cn]);
                float d  = __bfloat162float(rD[cn]);
                B[qr * 264 + cn]       = __float2bfloat16(s + gt * ef);
                B[qr * 264 + 128 + cn] = __float2bfloat16(d + gt * ef);
            }
        }
    }

    // ---- GEMM2: z1 = relu(LN([S'|D']@c1_w + b)) -> B[:,0:128] overlay ----
    {
        f32x4 acc[8] = {};
        bf16x8 fifo[4];
#pragma unroll
        for (int s = 0; s < 4; s++)
            fifo[s] = *(const bf16x8*)(c1_sw + ((size_t)s * 64 + l) * 8);
        bf16x8 acur = *(const bf16x8*)&B[ln15 * 264 + q8];
        bf16x8 anx;
#pragma unroll
        for (int s = 0; s < 64; s++) {
            int kc = s >> 3, i = s & 7;
            if (i == 0 && kc < 7)
                anx = *(const bf16x8*)&B[ln15 * 264 + (kc + 1) * 32 + q8];
            bf16x8 bcur = fifo[s & 3];
            if (s + 4 < 64)
                fifo[s & 3] = *(const bf16x8*)(c1_sw + ((size_t)(s + 4) * 64 + l) * 8);
            acc[i] = __builtin_amdgcn_mfma_f32_16x16x32_bf16(acur, bcur, acc[i], 0, 0, 0);
            if (i == 7) acur = anx;
        }
#pragma unroll
        for (int i = 0; i < 8; i++) {
            float cb = c1_b[i * 16 + ln15];
#pragma unroll
            for (int r = 0; r < 4; r++) acc[i][r] += cb;
        }
        float mean[4], rstd[4];
#pragma unroll
        for (int r = 0; r < 4; r++) {
            float p = 0.0f;
#pragma unroll
            for (int i = 0; i < 8; i++) p += acc[i][r];
            p += __shfl_xor(p, 1, 64); p += __shfl_xor(p, 2, 64);
            p += __shfl_xor(p, 4, 64); p += __shfl_xor(p, 8, 64);
            mean[r] = p * (1.0f / 128.0f);
        }
#pragma unroll
        for (int r = 0; r < 4; r++) {
            float q = 0.0f;
#pragma unroll
            for (int i = 0; i < 8; i++) { float d = acc[i][r] - mean[r]; q += d * d; }
            q += __shfl_xor(q, 1, 64); q += __shfl_xor(q, 2, 64);
            q += __shfl_xor(q, 4, 64); q += __shfl_xor(q, 8, 64);
            rstd[r] = rsqrtf(q * (1.0f / 128.0f) + 1e-5f);
        }
#pragma unroll
        for (int i = 0; i < 8; i++) {
            int cn = i * 16 + ln15;
            float g1 = cl1_g[cn], b1 = cl1_b[cn];
#pragma unroll
            for (int r = 0; r < 4; r++) {
                int qr = quad * 4 + r;
                float y = fmaxf((acc[i][r] - mean[r]) * rstd[r] * g1 + b1, 0.0f);
                B[qr * 264 + cn] = __float2bfloat16(y);
            }
        }
    }

    // ---- GEMM3: z2 = relu(LN(z1@c2_w + b)); out = z2@c3_w + c3_b ----
    {
        f32x4 acc[4] = {};
        bf16x8 fifo[4];
#pragma unroll
        for (int s = 0; s < 4; s++)
            fifo[s] = *(const bf16x8*)(c2_sw + ((size_t)s * 64 + l) * 8);
        bf16x8 acur = *(const bf16x8*)&B[ln15 * 264 + q8];
        bf16x8 anx;
#pragma unroll
        for (int s = 0; s < 16; s++) {
            int kc = s >> 2, i = s & 3;
            if (i == 0 && kc < 3)
                anx = *(const bf16x8*)&B[ln15 * 264 + (kc + 1) * 32 + q8];
            bf16x8 bcur = fifo[s & 3];
            if (s + 4 < 16)
                fifo[s & 3] = *(const bf16x8*)(c2_sw + ((size_t)(s + 4) * 64 + l) * 8);
            acc[i] = __builtin_amdgcn_mfma_f32_16x16x32_bf16(acur, bcur, acc[i], 0, 0, 0);
            if (i == 3) acur = anx;
        }
#pragma unroll
        for (int i = 0; i < 4; i++) {
            float cb = c2_b[i * 16 + ln15];
#pragma unroll
            for (int r = 0; r < 4; r++) acc[i][r] += cb;
        }
        float mean[4], rstd[4];
#pragma unroll
        for (int r = 0; r < 4; r++) {
            float p = 0.0f;
#pragma unroll
            for (int i = 0; i < 4; i++) p += acc[i][r];
            p += __shfl_xor(p, 1, 64); p += __shfl_xor(p, 2, 64);
            p += __shfl_xor(p, 4, 64); p += __shfl_xor(p, 8, 64);
            mean[r] = p * (1.0f / 64.0f);
        }
#pragma unroll
        for (int r = 0; r < 4; r++) {
            float q = 0.0f;
#pragma unroll
            for (int i = 0; i < 4; i++) { float d = acc[i][r] - mean[r]; q += d * d; }
            q += __shfl_xor(q, 1, 64); q += __shfl_xor(q, 2, 64);
            q += __shfl_xor(q, 4, 64); q += __shfl_xor(q, 8, 64);
            rstd[r] = rsqrtf(q * (1.0f / 64.0f) + 1e-5f);
        }
        float w0[4], w1[4];
#pragma unroll
        for (int i = 0; i < 4; i++) {
            float2 cw = *(const float2*)&c3_w[(i * 16 + ln15) * 2];
            w0[i] = cw.x; w1[i] = cw.y;
        }
#pragma unroll
        for (int r = 0; r < 4; r++) {
            float s0 = 0.0f, s1 = 0.0f;
#pragma unroll
            for (int i = 0; i < 4; i++) {
                int cn = i * 16 + ln15;
                float y = fmaxf((acc[i][r] - mean[r]) * rstd[r] * cl2_g[cn] + cl2_b[cn], 0.0f);
                s0 += y * w0[i];
                s1 += y * w1[i];
            }
            s0 += __shfl_xor(s0, 1, 64); s0 += __shfl_xor(s0, 2, 64);
            s0 += __shfl_xor(s0, 4, 64); s0 += __shfl_xor(s0, 8, 64);
            s1 += __shfl_xor(s1, 1, 64); s1 += __shfl_xor(s1, 2, 64);
            s1 += __shfl_xor(s1, 4, 64); s1 += __shfl_xor(s1, 8, 64);
            if (ln15 == 0) {
                int e = e0 + rbase + quad * 4 + r;
                if (e < E) {
                    float2 o; o.x = s0 + c3_b[0]; o.y = s1 + c3_b[1];
                    *(float2*)&out[(size_t)e * 2] = o;
                }
            }
        }
    }
}

extern "C" void kernel_launch(void* const* d_in, const int* in_sizes, int n_in,
                              void* d_out, int out_size, void* d_ws, size_t ws_size,
                              hipStream_t stream) {
    const float* x        = (const float*)d_in[0];
    const int*   eidx     = (const int*)d_in[1];
    const float* eattr    = (const float*)d_in[2];
    const float* ne_w     = (const float*)d_in[3];
    const float* ne_b     = (const float*)d_in[4];
    const float* ne_g     = (const float*)d_in[5];
    const float* ne_beta  = (const float*)d_in[6];
    const float* ee_w     = (const float*)d_in[7];
    const float* ee_b     = (const float*)d_in[8];
    const float* ee_g     = (const float*)d_in[9];
    const float* ee_beta  = (const float*)d_in[10];
    const float* gate_w   = (const float*)d_in[11];
    const float* gate_b   = (const float*)d_in[12];
    const float* gatA_w   = (const float*)d_in[13];
    const float* gatA_as  = (const float*)d_in[14];
    const float* gatA_ad  = (const float*)d_in[15];
    const float* gatA_bias= (const float*)d_in[16];
    const float* gatB_w   = (const float*)d_in[17];
    const float* gatB_as  = (const float*)d_in[18];
    const float* gatB_ad  = (const float*)d_in[19];
    const float* gatB_bias= (const float*)d_in[20];
    const float* ln_g     = (const float*)d_in[21];
    const float* ln_b     = (const float*)d_in[22];
    const float* c1_w     = (const float*)d_in[23];
    const float* c1_b     = (const float*)d_in[24];
    const float* cl1_g    = (const float*)d_in[25];
    const float* cl1_b    = (const float*)d_in[26];
    const float* c2_w     = (const float*)d_in[27];
    const float* c2_b     = (const float*)d_in[28];
    const float* cl2_g    = (const float*)d_in[29];
    const float* cl2_b    = (const float*)d_in[30];
    const float* c3_w     = (const float*)d_in[31];
    const float* c3_b     = (const float*)d_in[32];

    const int N = in_sizes[0] / NFEAT;
    const int E = in_sizes[1] / 2;
    const int E2 = E + N;
    const int* rowp = eidx;
    const int* colp = eidx + E;

    char* ws = (char*)d_ws;
    size_t off = 0;
    auto alloc = [&](size_t bytes) -> void* {
        void* p = ws + off;
        off = (off + bytes + 255) & ~(size_t)255;
        return p;
    };
    int*   deg    = (int*)alloc((size_t)N * 4);
    int*   cursor = (int*)alloc((size_t)N * 4);
    int*   offs   = (int*)alloc((size_t)(N + 1) * 4);
    int*   srcs   = (int*)alloc((size_t)E2 * 4);
    float* a_s    = (float*)alloc((size_t)N * 8 * 4);
    float* a_d    = (float*)alloc((size_t)N * 8 * 4);
    __hip_bfloat16* h_bfA  = (__hip_bfloat16*)alloc((size_t)N * H * 2);
    __hip_bfloat16* h_bfB  = (__hip_bfloat16*)alloc((size_t)N * H * 2);
    __hip_bfloat16* xp_bf  = (__hip_bfloat16*)alloc((size_t)N * H * 2);
    __hip_bfloat16* gate_sw= (__hip_bfloat16*)alloc((size_t)49152 * 2);
    __hip_bfloat16* c1_sw  = (__hip_bfloat16*)alloc((size_t)32768 * 2);
    __hip_bfloat16* c2_sw  = (__hip_bfloat16*)alloc((size_t)8192 * 2);
    __hip_bfloat16* wT3    = (__hip_bfloat16*)alloc((size_t)3 * 128 * 128 * 2);
    __hip_bfloat16* ee_sw  = (__hip_bfloat16*)alloc((size_t)4096 * 2);
    (void)ws_size;

    // weight prep
    k_wprep<<<(143360 + 255) / 256, 256, 0, stream>>>(gate_w, c1_w, c2_w, gatA_w, gatB_w, ee_w,
                                                      gate_sw, c1_sw, c2_sw, wT3, ee_sw);

    // CSR build
    hipMemsetAsync(deg, 0, (size_t)N * 4, stream);
    k_degree<<<(E2 + 255) / 256, 256, 0, stream>>>(colp, deg, E, N);
    k_scan<<<1, 1024, 0, stream>>>(deg, offs, cursor, N);
    k_scatter<<<(E2 + 255) / 256, 256, 0, stream>>>(rowp, colp, cursor, srcs, E, N);

    // node encoder -> bf16
    int ngrid = (N + 3) / 4;
    k_node_enc<<<ngrid, 256, 0, stream>>>(x, ne_w, ne_b, ne_g, ne_beta, h_bfA, N);

    int xpgrid = (N + 63) / 64;
    __hip_bfloat16* hin = h_bfA;
    __hip_bfloat16* hout = h_bfB;
    for (int l = 0; l < 2; l++) {
        k_gat_xp_mfma<<<xpgrid, 256, 0, stream>>>(hin, wT3 + (size_t)l * 16384,
                                                  gatA_as + l * H, gatA_ad + l * H,
                                                  xp_bf, a_s, a_d, 8, N);
        k_gat_agg<<<ngrid, 256, 0, stream>>>(xp_bf, a_s, a_d, offs, srcs,
                                             gatA_bias + l * H, ln_g + l * H, ln_b + l * H,
                                             hout, 8, N);
        __hip_bfloat16* tmp = hin; hin = hout; hout = tmp;
    }
    k_gat_xp_mfma<<<xpgrid, 256, 0, stream>>>(hin, wT3 + (size_t)2 * 16384,
                                              gatB_as, gatB_ad,
                                              xp_bf, a_s, a_d, 1, N);
    k_gat_agg<<<ngrid, 256, 0, stream>>>(xp_bf, a_s, a_d, offs, srcs,
                                         gatB_bias, ln_g + 2 * H, ln_b + 2 * H,
                                         hout, 1, N);

    // single-pass 4-GEMM MFMA edge classifier
    k_edge_cls_mfma<<<(E + 63) / 64, 256, 0, stream>>>(
        hout, rowp, colp, eattr,
        ee_sw, ee_b, ee_g, ee_beta,
        gate_sw, gate_b,
        c1_sw, c1_b, cl1_g, cl1_b,
        c2_sw, c2_b, cl2_g, cl2_b,
        c3_w, c3_b,
        (float*)d_out, E);
}

// Round 12
// 723.916 us; speedup vs baseline: 1.0073x; 1.0073x over previous
//
#include <hip/hip_runtime.h>
#include <hip/hip_bf16.h>

#define H 128
#define NFEAT 10
#define EFEAT 10

typedef __attribute__((ext_vector_type(8))) short bf16x8;
typedef __attribute__((ext_vector_type(4))) float f32x4;

__device__ __forceinline__ float bflo(unsigned v) { return __uint_as_float(v << 16); }
__device__ __forceinline__ float bfhi(unsigned v) { return __uint_as_float(v & 0xffff0000u); }
__device__ __forceinline__ unsigned bfpack(float a, float b) {
    __hip_bfloat16 h0 = __float2bfloat16(a), h1 = __float2bfloat16(b);
    return (unsigned)(*(unsigned short*)&h0) | ((unsigned)(*(unsigned short*)&h1) << 16);
}

// ---------------- CSR build ----------------
__global__ __launch_bounds__(256) void k_degree(const int* __restrict__ col,
                                                int* __restrict__ deg, int E, int N) {
    int i = blockIdx.x * blockDim.x + threadIdx.x;
    int E2 = E + N;
    if (i < E2) {
        int d = (i < E) ? col[i] : (i - E);
        atomicAdd(&deg[d], 1);
    }
}

__global__ __launch_bounds__(1024) void k_scan(const int* __restrict__ deg,
                                               int* __restrict__ offs,
                                               int* __restrict__ cursor, int N) {
    __shared__ int ps[1024];
    int t = threadIdx.x;
    int chunk = (N + 1023) / 1024;
    int begin = t * chunk;
    int end = begin + chunk; if (end > N) end = N;
    int s = 0;
    for (int i = begin; i < end; i++) s += deg[i];
    if (begin >= N) s = 0;
    ps[t] = s;
    __syncthreads();
    for (int off = 1; off < 1024; off <<= 1) {
        int v = (t >= off) ? ps[t - off] : 0;
        __syncthreads();
        ps[t] += v;
        __syncthreads();
    }
    int run = (t == 0) ? 0 : ps[t - 1];
    if (begin < N) {
        for (int i = begin; i < end; i++) {
            offs[i] = run;
            cursor[i] = run;
            run += deg[i];
        }
    }
    if (t == 1023) offs[N] = ps[1023];
}

__global__ __launch_bounds__(256) void k_scatter(const int* __restrict__ rowp,
                                                 const int* __restrict__ colp,
                                                 int* __restrict__ cursor,
                                                 int* __restrict__ srcs, int E, int N) {
    int i = blockIdx.x * blockDim.x + threadIdx.x;
    if (i < E + N) {
        int s, d;
        if (i < E) { s = rowp[i]; d = colp[i]; }
        else       { s = i - E;  d = i - E; }
        int pos = atomicAdd(&cursor[d], 1);
        srcs[pos] = s;
    }
}

// ---------------- Node encoder: 1 wave/node, lane = 2 features ----------------
__global__ __launch_bounds__(256) void k_node_enc(const float* __restrict__ x,
                                                  const float* __restrict__ wm,
                                                  const float* __restrict__ b,
                                                  const float* __restrict__ g,
                                                  const float* __restrict__ beta,
                                                  __hip_bfloat16* __restrict__ h, int N) {
    int t = threadIdx.x;
    int w = t >> 6, l = t & 63;
    int n = blockIdx.x * 4 + w;
    if (n >= N) return;
    float xs[NFEAT];
#pragma unroll
    for (int k = 0; k < NFEAT; k++) xs[k] = x[(size_t)n * NFEAT + k];
    float a0 = b[2 * l], a1 = b[2 * l + 1];
#pragma unroll
    for (int k = 0; k < NFEAT; k++) {
        float2 wv = *(const float2*)&wm[k * H + 2 * l];
        a0 += xs[k] * wv.x;
        a1 += xs[k] * wv.y;
    }
    float p = a0 + a1;
#pragma unroll
    for (int s = 1; s < 64; s <<= 1) p += __shfl_xor(p, s, 64);
    float mean = p * (1.0f / H);
    float d0 = a0 - mean, d1 = a1 - mean;
    float q = d0 * d0 + d1 * d1;
#pragma unroll
    for (int s = 1; s < 64; s <<= 1) q += __shfl_xor(q, s, 64);
    float rstd = rsqrtf(q * (1.0f / H) + 1e-5f);
    float y0 = fmaxf(d0 * rstd * g[2 * l] + beta[2 * l], 0.0f);
    float y1 = fmaxf(d1 * rstd * g[2 * l + 1] + beta[2 * l + 1], 0.0f);
    *(unsigned*)&h[(size_t)n * H + 2 * l] = bfpack(y0, y1);
}

// ---------------- GAT stage 1: MFMA xp = h@w, fused scores ----------------
__global__ __launch_bounds__(256, 2) void k_gat_xp_mfma(
        const __hip_bfloat16* __restrict__ h_bf,
        const __hip_bfloat16* __restrict__ wT,
        const float* __restrict__ asrc,
        const float* __restrict__ adst,
        __hip_bfloat16* __restrict__ xp_bf,
        float* __restrict__ a_s, float* __restrict__ a_d,
        int heads, int N) {
    __shared__ __hip_bfloat16 Ws[128 * 136];
    __shared__ __hip_bfloat16 As[64 * 136];
    int t = threadIdx.x;
    int n0 = blockIdx.x * 64;

#pragma unroll
    for (int it = 0; it < 2; it++) {
        int idx = it * 256 + t;
        int row = idx >> 2, seg = idx & 3;
        const uint4* src = (const uint4*)(wT + row * 128 + seg * 32);
        uint4 v0 = src[0], v1 = src[1], v2 = src[2], v3 = src[3];
        uint4* dst = (uint4*)&Ws[row * 136 + seg * 32];
        dst[0] = v0; dst[1] = v1; dst[2] = v2; dst[3] = v3;
    }
    {
        int row = t >> 2, seg = t & 3;
        int n = n0 + row; if (n >= N) n = N - 1;
        const uint4* src = (const uint4*)(h_bf + (size_t)n * 128 + seg * 32);
        uint4 v0 = src[0], v1 = src[1], v2 = src[2], v3 = src[3];
        uint4* dst = (uint4*)&As[row * 136 + seg * 32];
        dst[0] = v0; dst[1] = v1; dst[2] = v2; dst[3] = v3;
    }
    __syncthreads();

    int w = t >> 6, l = t & 63, ln15 = l & 15, quad = l >> 4, q8 = quad * 8;
    f32x4 acc[8] = {};
#pragma unroll
    for (int k = 0; k < 128; k += 32) {
        bf16x8 af = *(const bf16x8*)&As[(w * 16 + ln15) * 136 + k + q8];
#pragma unroll
        for (int i = 0; i < 8; i++) {
            bf16x8 bfr = *(const bf16x8*)&Ws[(i * 16 + ln15) * 136 + k + q8];
            acc[i] = __builtin_amdgcn_mfma_f32_16x16x32_bf16(af, bfr, acc[i], 0, 0, 0);
        }
    }

    if (heads == 8) {
#pragma unroll
        for (int i = 0; i < 8; i++) {
            float av = asrc[i * 16 + ln15], dvv = adst[i * 16 + ln15];
            float ps[4], pd[4];
#pragma unroll
            for (int r = 0; r < 4; r++) { ps[r] = acc[i][r] * av; pd[r] = acc[i][r] * dvv; }
#pragma unroll
            for (int s = 1; s < 16; s <<= 1) {
#pragma unroll
                for (int r = 0; r < 4; r++) {
                    ps[r] += __shfl_xor(ps[r], s, 64);
                    pd[r] += __shfl_xor(pd[r], s, 64);
                }
            }
            if (ln15 == 0) {
#pragma unroll
                for (int r = 0; r < 4; r++) {
                    int n = n0 + w * 16 + quad * 4 + r;
                    if (n < N) { a_s[(size_t)n * 8 + i] = ps[r]; a_d[(size_t)n * 8 + i] = pd[r]; }
                }
            }
        }
    } else {
        float ps[4] = {0, 0, 0, 0}, pd[4] = {0, 0, 0, 0};
#pragma unroll
        for (int i = 0; i < 8; i++) {
            float av = asrc[i * 16 + ln15], dvv = adst[i * 16 + ln15];
#pragma unroll
            for (int r = 0; r < 4; r++) { ps[r] += acc[i][r] * av; pd[r] += acc[i][r] * dvv; }
        }
#pragma unroll
        for (int s = 1; s < 16; s <<= 1) {
#pragma unroll
            for (int r = 0; r < 4; r++) {
                ps[r] += __shfl_xor(ps[r], s, 64);
                pd[r] += __shfl_xor(pd[r], s, 64);
            }
        }
        if (ln15 == 0) {
#pragma unroll
            for (int r = 0; r < 4; r++) {
                int n = n0 + w * 16 + quad * 4 + r;
                if (n < N) { a_s[n] = ps[r]; a_d[n] = pd[r]; }
            }
        }
    }

#pragma unroll
    for (int i = 0; i < 8; i++) {
#pragma unroll
        for (int r = 0; r < 4; r++) {
            int n = n0 + w * 16 + quad * 4 + r;
            if (n < N) xp_bf[(size_t)n * 128 + i * 16 + ln15] = __float2bfloat16(acc[i][r]);
        }
    }
}

// ---------------- GAT stage 2: 1 wave/node, 8x pipelined gather ----------------
__global__ __launch_bounds__(256) void k_gat_agg(const __hip_bfloat16* __restrict__ xp,
                                                 const float* __restrict__ a_s,
                                                 const float* __restrict__ a_d,
                                                 const int* __restrict__ offs,
                                                 const int* __restrict__ srcs,
                                                 const float* __restrict__ bias,
                                                 const float* __restrict__ g,
                                                 const float* __restrict__ b,
                                                 __hip_bfloat16* __restrict__ hout,
                                                 int heads, int N) {
    int t = threadIdx.x;
    int w = t >> 6, l = t & 63;
    int n = blockIdx.x * 4 + w;
    if (n >= N) return;
    int head = (heads == 8) ? (l >> 3) : 0;
    float adv = a_d[(size_t)n * heads + head];
    int s0 = offs[n], s1 = offs[n + 1];
    float acc0 = 0.0f, acc1 = 0.0f, den = 0.0f;
    int j = s0;
    for (; j + 8 <= s1; j += 8) {
        int s_[8];
#pragma unroll
        for (int u = 0; u < 8; u++) s_[u] = srcs[j + u];
        float e_[8]; unsigned v_[8];
#pragma unroll
        for (int u = 0; u < 8; u++) {
            e_[u] = a_s[(size_t)s_[u] * heads + head];
            v_[u] = *(const unsigned*)&xp[(size_t)s_[u] * H + 2 * l];
        }
#pragma unroll
        for (int u = 0; u < 8; u++) {
            float e = e_[u] + adv;
            e = (e >= 0.0f) ? e : 0.2f * e;
            float ex = __expf(e);
            den += ex;
            acc0 += ex * bflo(v_[u]);
            acc1 += ex * bfhi(v_[u]);
        }
    }
    for (; j < s1; j++) {
        int s = srcs[j];
        float e = a_s[(size_t)s * heads + head] + adv;
        e = (e >= 0.0f) ? e : 0.2f * e;
        float ex = __expf(e);
        den += ex;
        unsigned v = *(const unsigned*)&xp[(size_t)s * H + 2 * l];
        acc0 += ex * bflo(v);
        acc1 += ex * bfhi(v);
    }
    float inv = 1.0f / den;
    float v0 = acc0 * inv + bias[2 * l];
    float v1 = acc1 * inv + bias[2 * l + 1];
    float p = v0 + v1;
#pragma unroll
    for (int s = 1; s < 64; s <<= 1) p += __shfl_xor(p, s, 64);
    float mean = p * (1.0f / H);
    float d0 = v0 - mean, d1 = v1 - mean;
    float q = d0 * d0 + d1 * d1;
#pragma unroll
    for (int s = 1; s < 64; s <<= 1) q += __shfl_xor(q, s, 64);
    float rstd = rsqrtf(q * (1.0f / H) + 1e-5f);
    float y0 = fmaxf(d0 * rstd * g[2 * l] + b[2 * l], 0.0f);
    float y1 = fmaxf(d1 * rstd * g[2 * l + 1] + b[2 * l + 1], 0.0f);
    *(unsigned*)&hout[(size_t)n * H + 2 * l] = bfpack(y0, y1);
}

// ---------------- weight prep: fragment-swizzled bf16 ----------------
__global__ __launch_bounds__(256) void k_wprep(const float* __restrict__ gate_w,
                                               const float* __restrict__ c1_w,
                                               const float* __restrict__ c2_w,
                                               const float* __restrict__ gatA_w,
                                               const float* __restrict__ gatB_w,
                                               const float* __restrict__ ee_w,
                                               __hip_bfloat16* __restrict__ gate_sw,
                                               __hip_bfloat16* __restrict__ c1_sw,
                                               __hip_bfloat16* __restrict__ c2_sw,
                                               __hip_bfloat16* __restrict__ wT3,
                                               __hip_bfloat16* __restrict__ ee_sw) {
    int i = blockIdx.x * blockDim.x + threadIdx.x;
    if (i < 49152) {                       // gate
        int j = i & 7, lane = (i >> 3) & 63, rest = i >> 9;
        int nt = rest & 7, kc = rest >> 3;
        int n = nt * 16 + (lane & 15);
        int k = kc * 32 + (lane >> 4) * 8 + j;
        gate_sw[i] = __float2bfloat16(gate_w[k * 128 + n]);
    } else if (i < 81920) {                // c1
        int m = i - 49152;
        int j = m & 7, lane = (m >> 3) & 63, rest = m >> 9;
        int nt = rest & 7, kc = rest >> 3;
        int n = nt * 16 + (lane & 15);
        int k = kc * 32 + (lane >> 4) * 8 + j;
        c1_sw[m] = __float2bfloat16(c1_w[k * 128 + n]);
    } else if (i < 90112) {                // c2
        int m = i - 81920;
        int j = m & 7, lane = (m >> 3) & 63, rest = m >> 9;
        int nt = rest & 3, kc = rest >> 2;
        int n = nt * 16 + (lane & 15);
        int k = kc * 32 + (lane >> 4) * 8 + j;
        c2_sw[m] = __float2bfloat16(c2_w[k * 64 + n]);
    } else if (i < 139264) {               // gatA[0], gatA[1], gatB
        int m = i - 90112;
        int mat = m / 16384, r = m % 16384;
        int n = r / 128, k = r % 128;
        const float* src = (mat < 2) ? (gatA_w + (size_t)mat * 16384) : gatB_w;
        wT3[m] = __float2bfloat16(src[k * 128 + n]);
    } else if (i < 143360) {               // ee_sw (K padded to 32)
        int m = i - 139264;
        int j = m & 7, lane = (m >> 3) & 63, nt = (m >> 9) & 7;
        int n = nt * 16 + (lane & 15);
        int k = (lane >> 4) * 8 + j;
        ee_sw[m] = (k < EFEAT) ? __float2bfloat16(ee_w[k * 128 + n]) : __float2bfloat16(0.0f);
    }
}

// ---------------- Edge classifier: single-pass 4-GEMM MFMA MLP ----------------
// 64 edges/block, 4 waves; wave owns 16 edges + all N-tiles. No __syncthreads.
// Depth-4 B-frag FIFO; inline A-streams.
// __launch_bounds__(256) ONLY: no min-waves clause. Kernel needs ~84 regs/wave
// (52 arch + 32 acc); LDS 33.8 KB caps occupancy at 4 blocks/CU (16 waves) with
// zero spill. The (256,4) variant mis-capped arch VGPRs at 64 -> 40-70 MB
// scratch spill; (256,3) gave only 12 waves. This gets 16 waves AND no spill.
__global__ __launch_bounds__(256) void k_edge_cls_mfma(
        const __hip_bfloat16* __restrict__ h_bf,
        const int* __restrict__ rowp, const int* __restrict__ colp,
        const float* __restrict__ eattr,
        const __hip_bfloat16* __restrict__ ee_sw, const float* __restrict__ ee_b,
        const float* __restrict__ ee_g, const float* __restrict__ ee_beta,
        const __hip_bfloat16* __restrict__ gate_sw, const float* __restrict__ gate_b,
        const __hip_bfloat16* __restrict__ c1_sw, const float* __restrict__ c1_b,
        const float* __restrict__ cl1_g, const float* __restrict__ cl1_b,
        const __hip_bfloat16* __restrict__ c2_sw, const float* __restrict__ c2_b,
        const float* __restrict__ cl2_g, const float* __restrict__ cl2_b,
        const float* __restrict__ c3_w, const float* __restrict__ c3_b,
        float* __restrict__ out, int E) {
    __shared__ __align__(16) __hip_bfloat16 Bs[4 * 16 * 264];
    int t = threadIdx.x;
    int w = t >> 6, l = t & 63;
    int ln15 = l & 15, quad = l >> 4, q8 = quad * 8;
    int e0 = blockIdx.x * 64;
    int rbase = w * 16;
    __hip_bfloat16* B = Bs + w * (16 * 264);

    // fragment-row edge + node pointers (row = ln15)
    int eF = e0 + rbase + ln15; if (eF >= E) eF = E - 1;
    const __hip_bfloat16* rowS = h_bf + (size_t)rowp[eF] * 128;
    const __hip_bfloat16* rowD = h_bf + (size_t)colp[eF] * 128;

    // ---- GEMM0: Ef = relu(LN(ea @ ee_w + ee_b)) -> B[:,0:128] ----
    {
        bf16x8 afe;
#pragma unroll
        for (int j = 0; j < 8; j++) {
            int k = q8 + j;
            float v = (k < EFEAT) ? eattr[(size_t)eF * EFEAT + k] : 0.0f;
            __hip_bfloat16 hv = __float2bfloat16(v);
            afe[j] = *(short*)&hv;
        }
        f32x4 acc[8] = {};
#pragma unroll
        for (int i = 0; i < 8; i++) {
            bf16x8 bfr = *(const bf16x8*)(ee_sw + ((size_t)i * 64 + l) * 8);
            acc[i] = __builtin_amdgcn_mfma_f32_16x16x32_bf16(afe, bfr, acc[i], 0, 0, 0);
        }
#pragma unroll
        for (int i = 0; i < 8; i++) {
            float cb = ee_b[i * 16 + ln15];
#pragma unroll
            for (int r = 0; r < 4; r++) acc[i][r] += cb;
        }
        float mean[4], rstd[4];
#pragma unroll
        for (int r = 0; r < 4; r++) {
            float p = 0.0f;
#pragma unroll
            for (int i = 0; i < 8; i++) p += acc[i][r];
            p += __shfl_xor(p, 1, 64); p += __shfl_xor(p, 2, 64);
            p += __shfl_xor(p, 4, 64); p += __shfl_xor(p, 8, 64);
            mean[r] = p * (1.0f / 128.0f);
        }
#pragma unroll
        for (int r = 0; r < 4; r++) {
            float q = 0.0f;
#pragma unroll
            for (int i = 0; i < 8; i++) { float d = acc[i][r] - mean[r]; q += d * d; }
            q += __shfl_xor(q, 1, 64); q += __shfl_xor(q, 2, 64);
            q += __shfl_xor(q, 4, 64); q += __shfl_xor(q, 8, 64);
            rstd[r] = rsqrtf(q * (1.0f / 128.0f) + 1e-5f);
        }
#pragma unroll
        for (int i = 0; i < 8; i++) {
            int cn = i * 16 + ln15;
            float g1 = ee_g[cn], b1 = ee_beta[cn];
#pragma unroll
            for (int r = 0; r < 4; r++) {
                int qr = quad * 4 + r;
                float y = fmaxf((acc[i][r] - mean[r]) * rstd[r] * g1 + b1, 0.0f);
                B[qr * 264 + cn] = __float2bfloat16(y);
            }
        }
    }

    // ---- GEMM1: gate = sigmoid([S|D|Ef]@gate_w + b); B <- [S+g*Ef | D+g*Ef] ----
    {
        f32x4 acc[8] = {};
        bf16x8 fifo[4];
#pragma unroll
        for (int s = 0; s < 4; s++)
            fifo[s] = *(const bf16x8*)(gate_sw + ((size_t)s * 64 + l) * 8);
        bf16x8 acur = *(const bf16x8*)(rowS + q8);
        bf16x8 anx;
#pragma unroll
        for (int s = 0; s < 96; s++) {
            int kc = s >> 3, i = s & 7;
            if (i == 0 && kc < 11) {
                int k1 = kc + 1;
                if (k1 < 4)      anx = *(const bf16x8*)(rowS + k1 * 32 + q8);
                else if (k1 < 8) anx = *(const bf16x8*)(rowD + (k1 - 4) * 32 + q8);
                else             anx = *(const bf16x8*)&B[ln15 * 264 + (k1 - 8) * 32 + q8];
            }
            bf16x8 bcur = fifo[s & 3];
            if (s + 4 < 96)
                fifo[s & 3] = *(const bf16x8*)(gate_sw + ((size_t)(s + 4) * 64 + l) * 8);
            acc[i] = __builtin_amdgcn_mfma_f32_16x16x32_bf16(acur, bcur, acc[i], 0, 0, 0);
            if (i == 7) acur = anx;
        }
#pragma unroll
        for (int r = 0; r < 4; r++) {
            int qr = quad * 4 + r;
            int er = e0 + rbase + qr; if (er >= E) er = E - 1;
            const __hip_bfloat16* rS = h_bf + (size_t)rowp[er] * 128;
            const __hip_bfloat16* rD = h_bf + (size_t)colp[er] * 128;
#pragma unroll
            for (int i = 0; i < 8; i++) {
                int cn = i * 16 + ln15;
                float gt = 1.0f / (1.0f + __expf(-(acc[i][r] + gate_b[cn])));
                float ef = __bfloat162float(B[qr * 264 + cn]);   // Ef (read before overwrite)
                float s  = __bfloat162float(rS[cn]);
                float d  = __bfloat162float(rD[cn]);
                B[qr * 264 + cn]       = __float2bfloat16(s + gt * ef);
                B[qr * 264 + 128 + cn] = __float2bfloat16(d + gt * ef);
            }
        }
    }

    // ---- GEMM2: z1 = relu(LN([S'|D']@c1_w + b)) -> B[:,0:128] overlay ----
    {
        f32x4 acc[8] = {};
        bf16x8 fifo[4];
#pragma unroll
        for (int s = 0; s < 4; s++)
            fifo[s] = *(const bf16x8*)(c1_sw + ((size_t)s * 64 + l) * 8);
        bf16x8 acur = *(const bf16x8*)&B[ln15 * 264 + q8];
        bf16x8 anx;
#pragma unroll
        for (int s = 0; s < 64; s++) {
            int kc = s >> 3, i = s & 7;
            if (i == 0 && kc < 7)
                anx = *(const bf16x8*)&B[ln15 * 264 + (kc + 1) * 32 + q8];
            bf16x8 bcur = fifo[s & 3];
            if (s + 4 < 64)
                fifo[s & 3] = *(const bf16x8*)(c1_sw + ((size_t)(s + 4) * 64 + l) * 8);
            acc[i] = __builtin_amdgcn_mfma_f32_16x16x32_bf16(acur, bcur, acc[i], 0, 0, 0);
            if (i == 7) acur = anx;
        }
#pragma unroll
        for (int i = 0; i < 8; i++) {
            float cb = c1_b[i * 16 + ln15];
#pragma unroll
            for (int r = 0; r < 4; r++) acc[i][r] += cb;
        }
        float mean[4], rstd[4];
#pragma unroll
        for (int r = 0; r < 4; r++) {
            float p = 0.0f;
#pragma unroll
            for (int i = 0; i < 8; i++) p += acc[i][r];
            p += __shfl_xor(p, 1, 64); p += __shfl_xor(p, 2, 64);
            p += __shfl_xor(p, 4, 64); p += __shfl_xor(p, 8, 64);
            mean[r] = p * (1.0f / 128.0f);
        }
#pragma unroll
        for (int r = 0; r < 4; r++) {
            float q = 0.0f;
#pragma unroll
            for (int i = 0; i < 8; i++) { float d = acc[i][r] - mean[r]; q += d * d; }
            q += __shfl_xor(q, 1, 64); q += __shfl_xor(q, 2, 64);
            q += __shfl_xor(q, 4, 64); q += __shfl_xor(q, 8, 64);
            rstd[r] = rsqrtf(q * (1.0f / 128.0f) + 1e-5f);
        }
#pragma unroll
        for (int i = 0; i < 8; i++) {
            int cn = i * 16 + ln15;
            float g1 = cl1_g[cn], b1 = cl1_b[cn];
#pragma unroll
            for (int r = 0; r < 4; r++) {
                int qr = quad * 4 + r;
                float y = fmaxf((acc[i][r] - mean[r]) * rstd[r] * g1 + b1, 0.0f);
                B[qr * 264 + cn] = __float2bfloat16(y);
            }
        }
    }

    // ---- GEMM3: z2 = relu(LN(z1@c2_w + b)); out = z2@c3_w + c3_b ----
    {
        f32x4 acc[4] = {};
        bf16x8 fifo[4];
#pragma unroll
        for (int s = 0; s < 4; s++)
            fifo[s] = *(const bf16x8*)(c2_sw + ((size_t)s * 64 + l) * 8);
        bf16x8 acur = *(const bf16x8*)&B[ln15 * 264 + q8];
        bf16x8 anx;
#pragma unroll
        for (int s = 0; s < 16; s++) {
            int kc = s >> 2, i = s & 3;
            if (i == 0 && kc < 3)
                anx = *(const bf16x8*)&B[ln15 * 264 + (kc + 1) * 32 + q8];
            bf16x8 bcur = fifo[s & 3];
            if (s + 4 < 16)
                fifo[s & 3] = *(const bf16x8*)(c2_sw + ((size_t)(s + 4) * 64 + l) * 8);
            acc[i] = __builtin_amdgcn_mfma_f32_16x16x32_bf16(acur, bcur, acc[i], 0, 0, 0);
            if (i == 3) acur = anx;
        }
#pragma unroll
        for (int i = 0; i < 4; i++) {
            float cb = c2_b[i * 16 + ln15];
#pragma unroll
            for (int r = 0; r < 4; r++) acc[i][r] += cb;
        }
        float mean[4], rstd[4];
#pragma unroll
        for (int r = 0; r < 4; r++) {
            float p = 0.0f;
#pragma unroll
            for (int i = 0; i < 4; i++) p += acc[i][r];
            p += __shfl_xor(p, 1, 64); p += __shfl_xor(p, 2, 64);
            p += __shfl_xor(p, 4, 64); p += __shfl_xor(p, 8, 64);
            mean[r] = p * (1.0f / 64.0f);
        }
#pragma unroll
        for (int r = 0; r < 4; r++) {
            float q = 0.0f;
#pragma unroll
            for (int i = 0; i < 4; i++) { float d = acc[i][r] - mean[r]; q += d * d; }
            q += __shfl_xor(q, 1, 64); q += __shfl_xor(q, 2, 64);
            q += __shfl_xor(q, 4, 64); q += __shfl_xor(q, 8, 64);
            rstd[r] = rsqrtf(q * (1.0f / 64.0f) + 1e-5f);
        }
        float w0[4], w1[4];
#pragma unroll
        for (int i = 0; i < 4; i++) {
            float2 cw = *(const float2*)&c3_w[(i * 16 + ln15) * 2];
            w0[i] = cw.x; w1[i] = cw.y;
        }
#pragma unroll
        for (int r = 0; r < 4; r++) {
            float s0 = 0.0f, s1 = 0.0f;
#pragma unroll
            for (int i = 0; i < 4; i++) {
                int cn = i * 16 + ln15;
                float y = fmaxf((acc[i][r] - mean[r]) * rstd[r] * cl2_g[cn] + cl2_b[cn], 0.0f);
                s0 += y * w0[i];
                s1 += y * w1[i];
            }
            s0 += __shfl_xor(s0, 1, 64); s0 += __shfl_xor(s0, 2, 64);
            s0 += __shfl_xor(s0, 4, 64); s0 += __shfl_xor(s0, 8, 64);
            s1 += __shfl_xor(s1, 1, 64); s1 += __shfl_xor(s1, 2, 64);
            s1 += __shfl_xor(s1, 4, 64); s1 += __shfl_xor(s1, 8, 64);
            if (ln15 == 0) {
                int e = e0 + rbase + quad * 4 + r;
                if (e < E) {
                    float2 o; o.x = s0 + c3_b[0]; o.y = s1 + c3_b[1];
                    *(float2*)&out[(size_t)e * 2] = o;
                }
            }
        }
    }
}

extern "C" void kernel_launch(void* const* d_in, const int* in_sizes, int n_in,
                              void* d_out, int out_size, void* d_ws, size_t ws_size,
                              hipStream_t stream) {
    const float* x        = (const float*)d_in[0];
    const int*   eidx     = (const int*)d_in[1];
    const float* eattr    = (const float*)d_in[2];
    const float* ne_w     = (const float*)d_in[3];
    const float* ne_b     = (const float*)d_in[4];
    const float* ne_g     = (const float*)d_in[5];
    const float* ne_beta  = (const float*)d_in[6];
    const float* ee_w     = (const float*)d_in[7];
    const float* ee_b     = (const float*)d_in[8];
    const float* ee_g     = (const float*)d_in[9];
    const float* ee_beta  = (const float*)d_in[10];
    const float* gate_w   = (const float*)d_in[11];
    const float* gate_b   = (const float*)d_in[12];
    const float* gatA_w   = (const float*)d_in[13];
    const float* gatA_as  = (const float*)d_in[14];
    const float* gatA_ad  = (const float*)d_in[15];
    const float* gatA_bias= (const float*)d_in[16];
    const float* gatB_w   = (const float*)d_in[17];
    const float* gatB_as  = (const float*)d_in[18];
    const float* gatB_ad  = (const float*)d_in[19];
    const float* gatB_bias= (const float*)d_in[20];
    const float* ln_g     = (const float*)d_in[21];
    const float* ln_b     = (const float*)d_in[22];
    const float* c1_w     = (const float*)d_in[23];
    const float* c1_b     = (const float*)d_in[24];
    const float* cl1_g    = (const float*)d_in[25];
    const float* cl1_b    = (const float*)d_in[26];
    const float* c2_w     = (const float*)d_in[27];
    const float* c2_b     = (const float*)d_in[28];
    const float* cl2_g    = (const float*)d_in[29];
    const float* cl2_b    = (const float*)d_in[30];
    const float* c3_w     = (const float*)d_in[31];
    const float* c3_b     = (const float*)d_in[32];

    const int N = in_sizes[0] / NFEAT;
    const int E = in_sizes[1] / 2;
    const int E2 = E + N;
    const int* rowp = eidx;
    const int* colp = eidx + E;

    char* ws = (char*)d_ws;
    size_t off = 0;
    auto alloc = [&](size_t bytes) -> void* {
        void* p = ws + off;
        off = (off + bytes + 255) & ~(size_t)255;
        return p;
    };
    int*   deg    = (int*)alloc((size_t)N * 4);
    int*   cursor = (int*)alloc((size_t)N * 4);
    int*   offs   = (int*)alloc((size_t)(N + 1) * 4);
    int*   srcs   = (int*)alloc((size_t)E2 * 4);
    float* a_s    = (float*)alloc((size_t)N * 8 * 4);
    float* a_d    = (float*)alloc((size_t)N * 8 * 4);
    __hip_bfloat16* h_bfA  = (__hip_bfloat16*)alloc((size_t)N * H * 2);
    __hip_bfloat16* h_bfB  = (__hip_bfloat16*)alloc((size_t)N * H * 2);
    __hip_bfloat16* xp_bf  = (__hip_bfloat16*)alloc((size_t)N * H * 2);
    __hip_bfloat16* gate_sw= (__hip_bfloat16*)alloc((size_t)49152 * 2);
    __hip_bfloat16* c1_sw  = (__hip_bfloat16*)alloc((size_t)32768 * 2);
    __hip_bfloat16* c2_sw  = (__hip_bfloat16*)alloc((size_t)8192 * 2);
    __hip_bfloat16* wT3    = (__hip_bfloat16*)alloc((size_t)3 * 128 * 128 * 2);
    __hip_bfloat16* ee_sw  = (__hip_bfloat16*)alloc((size_t)4096 * 2);
    (void)ws_size;

    // weight prep
    k_wprep<<<(143360 + 255) / 256, 256, 0, stream>>>(gate_w, c1_w, c2_w, gatA_w, gatB_w, ee_w,
                                                      gate_sw, c1_sw, c2_sw, wT3, ee_sw);

    // CSR build
    hipMemsetAsync(deg, 0, (size_t)N * 4, stream);
    k_degree<<<(E2 + 255) / 256, 256, 0, stream>>>(colp, deg, E, N);
    k_scan<<<1, 1024, 0, stream>>>(deg, offs, cursor, N);
    k_scatter<<<(E2 + 255) / 256, 256, 0, stream>>>(rowp, colp, cursor, srcs, E, N);

    // node encoder -> bf16
    int ngrid = (N + 3) / 4;
    k_node_enc<<<ngrid, 256, 0, stream>>>(x, ne_w, ne_b, ne_g, ne_beta, h_bfA, N);

    int xpgrid = (N + 63) / 64;
    __hip_bfloat16* hin = h_bfA;
    __hip_bfloat16* hout = h_bfB;
    for (int l = 0; l < 2; l++) {
        k_gat_xp_mfma<<<xpgrid, 256, 0, stream>>>(hin, wT3 + (size_t)l * 16384,
                                                  gatA_as + l * H, gatA_ad + l * H,
                                                  xp_bf, a_s, a_d, 8, N);
        k_gat_agg<<<ngrid, 256, 0, stream>>>(xp_bf, a_s, a_d, offs, srcs,
                                             gatA_bias + l * H, ln_g + l * H, ln_b + l * H,
                                             hout, 8, N);
        __hip_bfloat16* tmp = hin; hin = hout; hout = tmp;
    }
    k_gat_xp_mfma<<<xpgrid, 256, 0, stream>>>(hin, wT3 + (size_t)2 * 16384,
                                              gatB_as, gatB_ad,
                                              xp_bf, a_s, a_d, 1, N);
    k_gat_agg<<<ngrid, 256, 0, stream>>>(xp_bf, a_s, a_d, offs, srcs,
                                         gatB_bias, ln_g + 2 * H, ln_b + 2 * H,
                                         hout, 1, N);

    // single-pass 4-GEMM MFMA edge classifier
    k_edge_cls_mfma<<<(E + 63) / 64, 256, 0, stream>>>(
        hout, rowp, colp, eattr,
        ee_sw, ee_b, ee_g, ee_beta,
        gate_sw, gate_b,
        c1_sw, c1_b, cl1_g, cl1_b,
        c2_sw, c2_b, cl2_g, cl2_b,
        c3_w, c3_b,
        (float*)d_out, E);
}

// Round 13
// 680.060 us; speedup vs baseline: 1.0723x; 1.0645x over previous
//
#include <hip/hip_runtime.h>
#include <hip/hip_bf16.h>

#define H 128
#define NFEAT 10
#define EFEAT 10
#define XPS 144   // packed xp row stride in bf16: 128 vals + 8 f32 scores

typedef __attribute__((ext_vector_type(8))) short bf16x8;
typedef __attribute__((ext_vector_type(4))) float f32x4;

__device__ __forceinline__ float bflo(unsigned v) { return __uint_as_float(v << 16); }
__device__ __forceinline__ float bfhi(unsigned v) { return __uint_as_float(v & 0xffff0000u); }
__device__ __forceinline__ unsigned bfpack(float a, float b) {
    __hip_bfloat16 h0 = __float2bfloat16(a), h1 = __float2bfloat16(b);
    return (unsigned)(*(unsigned short*)&h0) | ((unsigned)(*(unsigned short*)&h1) << 16);
}

// ---------------- CSR build ----------------
__global__ __launch_bounds__(256) void k_degree(const int* __restrict__ col,
                                                int* __restrict__ deg, int E, int N) {
    int i = blockIdx.x * blockDim.x + threadIdx.x;
    int E2 = E + N;
    if (i < E2) {
        int d = (i < E) ? col[i] : (i - E);
        atomicAdd(&deg[d], 1);
    }
}

__global__ __launch_bounds__(1024) void k_scan(const int* __restrict__ deg,
                                               int* __restrict__ offs,
                                               int* __restrict__ cursor, int N) {
    __shared__ int ps[1024];
    int t = threadIdx.x;
    int chunk = (N + 1023) / 1024;
    int begin = t * chunk;
    int end = begin + chunk; if (end > N) end = N;
    int s = 0;
    for (int i = begin; i < end; i++) s += deg[i];
    if (begin >= N) s = 0;
    ps[t] = s;
    __syncthreads();
    for (int off = 1; off < 1024; off <<= 1) {
        int v = (t >= off) ? ps[t - off] : 0;
        __syncthreads();
        ps[t] += v;
        __syncthreads();
    }
    int run = (t == 0) ? 0 : ps[t - 1];
    if (begin < N) {
        for (int i = begin; i < end; i++) {
            offs[i] = run;
            cursor[i] = run;
            run += deg[i];
        }
    }
    if (t == 1023) offs[N] = ps[1023];
}

__global__ __launch_bounds__(256) void k_scatter(const int* __restrict__ rowp,
                                                 const int* __restrict__ colp,
                                                 int* __restrict__ cursor,
                                                 int* __restrict__ srcs, int E, int N) {
    int i = blockIdx.x * blockDim.x + threadIdx.x;
    if (i < E + N) {
        int s, d;
        if (i < E) { s = rowp[i]; d = colp[i]; }
        else       { s = i - E;  d = i - E; }
        int pos = atomicAdd(&cursor[d], 1);
        srcs[pos] = s;
    }
}

// ---------------- Node encoder: 1 wave/node, lane = 2 features ----------------
__global__ __launch_bounds__(256) void k_node_enc(const float* __restrict__ x,
                                                  const float* __restrict__ wm,
                                                  const float* __restrict__ b,
                                                  const float* __restrict__ g,
                                                  const float* __restrict__ beta,
                                                  __hip_bfloat16* __restrict__ h, int N) {
    int t = threadIdx.x;
    int w = t >> 6, l = t & 63;
    int n = blockIdx.x * 4 + w;
    if (n >= N) return;
    float xs[NFEAT];
#pragma unroll
    for (int k = 0; k < NFEAT; k++) xs[k] = x[(size_t)n * NFEAT + k];
    float a0 = b[2 * l], a1 = b[2 * l + 1];
#pragma unroll
    for (int k = 0; k < NFEAT; k++) {
        float2 wv = *(const float2*)&wm[k * H + 2 * l];
        a0 += xs[k] * wv.x;
        a1 += xs[k] * wv.y;
    }
    float p = a0 + a1;
#pragma unroll
    for (int s = 1; s < 64; s <<= 1) p += __shfl_xor(p, s, 64);
    float mean = p * (1.0f / H);
    float d0 = a0 - mean, d1 = a1 - mean;
    float q = d0 * d0 + d1 * d1;
#pragma unroll
    for (int s = 1; s < 64; s <<= 1) q += __shfl_xor(q, s, 64);
    float rstd = rsqrtf(q * (1.0f / H) + 1e-5f);
    float y0 = fmaxf(d0 * rstd * g[2 * l] + beta[2 * l], 0.0f);
    float y1 = fmaxf(d1 * rstd * g[2 * l + 1] + beta[2 * l + 1], 0.0f);
    *(unsigned*)&h[(size_t)n * H + 2 * l] = bfpack(y0, y1);
}

// ---------------- GAT stage 1: MFMA xp = h@w, fused scores (packed rows) ----------------
// xp rows stride XPS=144 bf16: [0:128) values, [128:144) = 8 f32 a_s scores.
__global__ __launch_bounds__(256, 2) void k_gat_xp_mfma(
        const __hip_bfloat16* __restrict__ h_bf,
        const __hip_bfloat16* __restrict__ wT,
        const float* __restrict__ asrc,
        const float* __restrict__ adst,
        __hip_bfloat16* __restrict__ xp_bf,
        float* __restrict__ a_d,
        int heads, int N) {
    __shared__ __hip_bfloat16 Ws[128 * 136];
    __shared__ __hip_bfloat16 As[64 * 136];
    int t = threadIdx.x;
    int n0 = blockIdx.x * 64;

#pragma unroll
    for (int it = 0; it < 2; it++) {
        int idx = it * 256 + t;
        int row = idx >> 2, seg = idx & 3;
        const uint4* src = (const uint4*)(wT + row * 128 + seg * 32);
        uint4 v0 = src[0], v1 = src[1], v2 = src[2], v3 = src[3];
        uint4* dst = (uint4*)&Ws[row * 136 + seg * 32];
        dst[0] = v0; dst[1] = v1; dst[2] = v2; dst[3] = v3;
    }
    {
        int row = t >> 2, seg = t & 3;
        int n = n0 + row; if (n >= N) n = N - 1;
        const uint4* src = (const uint4*)(h_bf + (size_t)n * 128 + seg * 32);
        uint4 v0 = src[0], v1 = src[1], v2 = src[2], v3 = src[3];
        uint4* dst = (uint4*)&As[row * 136 + seg * 32];
        dst[0] = v0; dst[1] = v1; dst[2] = v2; dst[3] = v3;
    }
    __syncthreads();

    int w = t >> 6, l = t & 63, ln15 = l & 15, quad = l >> 4, q8 = quad * 8;
    f32x4 acc[8] = {};
#pragma unroll
    for (int k = 0; k < 128; k += 32) {
        bf16x8 af = *(const bf16x8*)&As[(w * 16 + ln15) * 136 + k + q8];
#pragma unroll
        for (int i = 0; i < 8; i++) {
            bf16x8 bfr = *(const bf16x8*)&Ws[(i * 16 + ln15) * 136 + k + q8];
            acc[i] = __builtin_amdgcn_mfma_f32_16x16x32_bf16(af, bfr, acc[i], 0, 0, 0);
        }
    }

    if (heads == 8) {
#pragma unroll
        for (int i = 0; i < 8; i++) {
            float av = asrc[i * 16 + ln15], dvv = adst[i * 16 + ln15];
            float ps[4], pd[4];
#pragma unroll
            for (int r = 0; r < 4; r++) { ps[r] = acc[i][r] * av; pd[r] = acc[i][r] * dvv; }
#pragma unroll
            for (int s = 1; s < 16; s <<= 1) {
#pragma unroll
                for (int r = 0; r < 4; r++) {
                    ps[r] += __shfl_xor(ps[r], s, 64);
                    pd[r] += __shfl_xor(pd[r], s, 64);
                }
            }
            if (ln15 == 0) {
#pragma unroll
                for (int r = 0; r < 4; r++) {
                    int n = n0 + w * 16 + quad * 4 + r;
                    if (n < N) {
                        *(float*)&xp_bf[(size_t)n * XPS + 128 + 2 * i] = ps[r];
                        a_d[(size_t)n * 8 + i] = pd[r];
                    }
                }
            }
        }
    } else {
        float ps[4] = {0, 0, 0, 0}, pd[4] = {0, 0, 0, 0};
#pragma unroll
        for (int i = 0; i < 8; i++) {
            float av = asrc[i * 16 + ln15], dvv = adst[i * 16 + ln15];
#pragma unroll
            for (int r = 0; r < 4; r++) { ps[r] += acc[i][r] * av; pd[r] += acc[i][r] * dvv; }
        }
#pragma unroll
        for (int s = 1; s < 16; s <<= 1) {
#pragma unroll
            for (int r = 0; r < 4; r++) {
                ps[r] += __shfl_xor(ps[r], s, 64);
                pd[r] += __shfl_xor(pd[r], s, 64);
            }
        }
        if (ln15 == 0) {
#pragma unroll
            for (int r = 0; r < 4; r++) {
                int n = n0 + w * 16 + quad * 4 + r;
                if (n < N) {
                    *(float*)&xp_bf[(size_t)n * XPS + 128] = ps[r];
                    a_d[n] = pd[r];
                }
            }
        }
    }

#pragma unroll
    for (int i = 0; i < 8; i++) {
#pragma unroll
        for (int r = 0; r < 4; r++) {
            int n = n0 + w * 16 + quad * 4 + r;
            if (n < N) xp_bf[(size_t)n * XPS + i * 16 + ln15] = __float2bfloat16(acc[i][r]);
        }
    }
}

// ---------------- GAT stage 2: 1 wave/node, packed-row gather ----------------
__global__ __launch_bounds__(256) void k_gat_agg(const __hip_bfloat16* __restrict__ xp,
                                                 const float* __restrict__ a_d,
                                                 const int* __restrict__ offs,
                                                 const int* __restrict__ srcs,
                                                 const float* __restrict__ bias,
                                                 const float* __restrict__ g,
                                                 const float* __restrict__ b,
                                                 __hip_bfloat16* __restrict__ hout,
                                                 int heads, int N) {
    int t = threadIdx.x;
    int w = t >> 6, l = t & 63;
    int n = blockIdx.x * 4 + w;
    if (n >= N) return;
    int head = (heads == 8) ? (l >> 3) : 0;
    float adv = a_d[(size_t)n * heads + head];
    int s0 = offs[n], s1 = offs[n + 1];
    float acc0 = 0.0f, acc1 = 0.0f, den = 0.0f;
    int j = s0;
    for (; j + 4 <= s1; j += 4) {
        int s_[4];
#pragma unroll
        for (int u = 0; u < 4; u++) s_[u] = srcs[j + u];
        float e_[4]; unsigned v_[4];
#pragma unroll
        for (int u = 0; u < 4; u++) {
            const __hip_bfloat16* xr = xp + (size_t)s_[u] * XPS;
            e_[u] = ((const float*)xr)[64 + head];   // score packed in row tail (same lines)
            v_[u] = *(const unsigned*)&xr[2 * l];
        }
#pragma unroll
        for (int u = 0; u < 4; u++) {
            float e = e_[u] + adv;
            e = (e >= 0.0f) ? e : 0.2f * e;
            float ex = __expf(e);
            den += ex;
            acc0 += ex * bflo(v_[u]);
            acc1 += ex * bfhi(v_[u]);
        }
    }
    for (; j < s1; j++) {
        int s = srcs[j];
        const __hip_bfloat16* xr = xp + (size_t)s * XPS;
        float e = ((const float*)xr)[64 + head] + adv;
        e = (e >= 0.0f) ? e : 0.2f * e;
        float ex = __expf(e);
        den += ex;
        unsigned v = *(const unsigned*)&xr[2 * l];
        acc0 += ex * bflo(v);
        acc1 += ex * bfhi(v);
    }
    float inv = 1.0f / den;
    float v0 = acc0 * inv + bias[2 * l];
    float v1 = acc1 * inv + bias[2 * l + 1];
    float p = v0 + v1;
#pragma unroll
    for (int s = 1; s < 64; s <<= 1) p += __shfl_xor(p, s, 64);
    float mean = p * (1.0f / H);
    float d0 = v0 - mean, d1 = v1 - mean;
    float q = d0 * d0 + d1 * d1;
#pragma unroll
    for (int s = 1; s < 64; s <<= 1) q += __shfl_xor(q, s, 64);
    float rstd = rsqrtf(q * (1.0f / H) + 1e-5f);
    float y0 = fmaxf(d0 * rstd * g[2 * l] + b[2 * l], 0.0f);
    float y1 = fmaxf(d1 * rstd * g[2 * l + 1] + b[2 * l + 1], 0.0f);
    *(unsigned*)&hout[(size_t)n * H + 2 * l] = bfpack(y0, y1);
}

// ---------------- weight prep: fragment-swizzled bf16 ----------------
__global__ __launch_bounds__(256) void k_wprep(const float* __restrict__ gate_w,
                                               const float* __restrict__ c1_w,
                                               const float* __restrict__ c2_w,
                                               const float* __restrict__ gatA_w,
                                               const float* __restrict__ gatB_w,
                                               const float* __restrict__ ee_w,
                                               __hip_bfloat16* __restrict__ gate_sw,
                                               __hip_bfloat16* __restrict__ c1_sw,
                                               __hip_bfloat16* __restrict__ c2_sw,
                                               __hip_bfloat16* __restrict__ wT3,
                                               __hip_bfloat16* __restrict__ ee_sw) {
    int i = blockIdx.x * blockDim.x + threadIdx.x;
    if (i < 49152) {                       // gate
        int j = i & 7, lane = (i >> 3) & 63, rest = i >> 9;
        int nt = rest & 7, kc = rest >> 3;
        int n = nt * 16 + (lane & 15);
        int k = kc * 32 + (lane >> 4) * 8 + j;
        gate_sw[i] = __float2bfloat16(gate_w[k * 128 + n]);
    } else if (i < 81920) {                // c1
        int m = i - 49152;
        int j = m & 7, lane = (m >> 3) & 63, rest = m >> 9;
        int nt = rest & 7, kc = rest >> 3;
        int n = nt * 16 + (lane & 15);
        int k = kc * 32 + (lane >> 4) * 8 + j;
        c1_sw[m] = __float2bfloat16(c1_w[k * 128 + n]);
    } else if (i < 90112) {                // c2
        int m = i - 81920;
        int j = m & 7, lane = (m >> 3) & 63, rest = m >> 9;
        int nt = rest & 3, kc = rest >> 2;
        int n = nt * 16 + (lane & 15);
        int k = kc * 32 + (lane >> 4) * 8 + j;
        c2_sw[m] = __float2bfloat16(c2_w[k * 64 + n]);
    } else if (i < 139264) {               // gatA[0], gatA[1], gatB
        int m = i - 90112;
        int mat = m / 16384, r = m % 16384;
        int n = r / 128, k = r % 128;
        const float* src = (mat < 2) ? (gatA_w + (size_t)mat * 16384) : gatB_w;
        wT3[m] = __float2bfloat16(src[k * 128 + n]);
    } else if (i < 143360) {               // ee_sw (K padded to 32)
        int m = i - 139264;
        int j = m & 7, lane = (m >> 3) & 63, nt = (m >> 9) & 7;
        int n = nt * 16 + (lane & 15);
        int k = (lane >> 4) * 8 + j;
        ee_sw[m] = (k < EFEAT) ? __float2bfloat16(ee_w[k * 128 + n]) : __float2bfloat16(0.0f);
    }
}

// ---------------- Edge classifier: single-pass 4-GEMM MFMA MLP (R9 config) ----------------
// 64 edges/block, 4 waves; wave owns 16 edges + all N-tiles. No __syncthreads.
// Depth-4 B-frag FIFO, inline A-streams, __launch_bounds__(256,4).
// NOTE: (256,4) caps arch VGPR at 64 and causes ~40 MB scratch spill/dispatch —
// measured FASTER (245 µs) than spill-free (256,3)=282 or (256)=275 at the same
// 16 waves/CU: the AGPR-heavy allocation schedules better. Keep it.
__global__ __launch_bounds__(256, 4) void k_edge_cls_mfma(
        const __hip_bfloat16* __restrict__ h_bf,
        const int* __restrict__ rowp, const int* __restrict__ colp,
        const float* __restrict__ eattr,
        const __hip_bfloat16* __restrict__ ee_sw, const float* __restrict__ ee_b,
        const float* __restrict__ ee_g, const float* __restrict__ ee_beta,
        const __hip_bfloat16* __restrict__ gate_sw, const float* __restrict__ gate_b,
        const __hip_bfloat16* __restrict__ c1_sw, const float* __restrict__ c1_b,
        const float* __restrict__ cl1_g, const float* __restrict__ cl1_b,
        const __hip_bfloat16* __restrict__ c2_sw, const float* __restrict__ c2_b,
        const float* __restrict__ cl2_g, const float* __restrict__ cl2_b,
        const float* __restrict__ c3_w, const float* __restrict__ c3_b,
        float* __restrict__ out, int E) {
    __shared__ __align__(16) __hip_bfloat16 Bs[4 * 16 * 264];
    int t = threadIdx.x;
    int w = t >> 6, l = t & 63;
    int ln15 = l & 15, quad = l >> 4, q8 = quad * 8;
    int e0 = blockIdx.x * 64;
    int rbase = w * 16;
    __hip_bfloat16* B = Bs + w * (16 * 264);

    // fragment-row edge + node pointers (row = ln15)
    int eF = e0 + rbase + ln15; if (eF >= E) eF = E - 1;
    const __hip_bfloat16* rowS = h_bf + (size_t)rowp[eF] * 128;
    const __hip_bfloat16* rowD = h_bf + (size_t)colp[eF] * 128;

    // ---- GEMM0: Ef = relu(LN(ea @ ee_w + ee_b)) -> B[:,0:128] ----
    {
        bf16x8 afe;
#pragma unroll
        for (int j = 0; j < 8; j++) {
            int k = q8 + j;
            float v = (k < EFEAT) ? eattr[(size_t)eF * EFEAT + k] : 0.0f;
            __hip_bfloat16 hv = __float2bfloat16(v);
            afe[j] = *(short*)&hv;
        }
        f32x4 acc[8] = {};
#pragma unroll
        for (int i = 0; i < 8; i++) {
            bf16x8 bfr = *(const bf16x8*)(ee_sw + ((size_t)i * 64 + l) * 8);
            acc[i] = __builtin_amdgcn_mfma_f32_16x16x32_bf16(afe, bfr, acc[i], 0, 0, 0);
        }
#pragma unroll
        for (int i = 0; i < 8; i++) {
            float cb = ee_b[i * 16 + ln15];
#pragma unroll
            for (int r = 0; r < 4; r++) acc[i][r] += cb;
        }
        float mean[4], rstd[4];
#pragma unroll
        for (int r = 0; r < 4; r++) {
            float p = 0.0f;
#pragma unroll
            for (int i = 0; i < 8; i++) p += acc[i][r];
            p += __shfl_xor(p, 1, 64); p += __shfl_xor(p, 2, 64);
            p += __shfl_xor(p, 4, 64); p += __shfl_xor(p, 8, 64);
            mean[r] = p * (1.0f / 128.0f);
        }
#pragma unroll
        for (int r = 0; r < 4; r++) {
            float q = 0.0f;
#pragma unroll
            for (int i = 0; i < 8; i++) { float d = acc[i][r] - mean[r]; q += d * d; }
            q += __shfl_xor(q, 1, 64); q += __shfl_xor(q, 2, 64);
            q += __shfl_xor(q, 4, 64); q += __shfl_xor(q, 8, 64);
            rstd[r] = rsqrtf(q * (1.0f / 128.0f) + 1e-5f);
        }
#pragma unroll
        for (int i = 0; i < 8; i++) {
            int cn = i * 16 + ln15;
            float g1 = ee_g[cn], b1 = ee_beta[cn];
#pragma unroll
            for (int r = 0; r < 4; r++) {
                int qr = quad * 4 + r;
                float y = fmaxf((acc[i][r] - mean[r]) * rstd[r] * g1 + b1, 0.0f);
                B[qr * 264 + cn] = __float2bfloat16(y);
            }
        }
    }

    // ---- GEMM1: gate = sigmoid([S|D|Ef]@gate_w + b); B <- [S+g*Ef | D+g*Ef] ----
    {
        f32x4 acc[8] = {};
        bf16x8 fifo[4];
#pragma unroll
        for (int s = 0; s < 4; s++)
            fifo[s] = *(const bf16x8*)(gate_sw + ((size_t)s * 64 + l) * 8);
        bf16x8 acur = *(const bf16x8*)(rowS + q8);
        bf16x8 anx;
#pragma unroll
        for (int s = 0; s < 96; s++) {
            int kc = s >> 3, i = s & 7;
            if (i == 0 && kc < 11) {
                int k1 = kc + 1;
                if (k1 < 4)      anx = *(const bf16x8*)(rowS + k1 * 32 + q8);
                else if (k1 < 8) anx = *(const bf16x8*)(rowD + (k1 - 4) * 32 + q8);
                else             anx = *(const bf16x8*)&B[ln15 * 264 + (k1 - 8) * 32 + q8];
            }
            bf16x8 bcur = fifo[s & 3];
            if (s + 4 < 96)
                fifo[s & 3] = *(const bf16x8*)(gate_sw + ((size_t)(s + 4) * 64 + l) * 8);
            acc[i] = __builtin_amdgcn_mfma_f32_16x16x32_bf16(acur, bcur, acc[i], 0, 0, 0);
            if (i == 7) acur = anx;
        }
#pragma unroll
        for (int r = 0; r < 4; r++) {
            int qr = quad * 4 + r;
            int er = e0 + rbase + qr; if (er >= E) er = E - 1;
            const __hip_bfloat16* rS = h_bf + (size_t)rowp[er] * 128;
            const __hip_bfloat16* rD = h_bf + (size_t)colp[er] * 128;
#pragma unroll
            for (int i = 0; i < 8; i++) {
                int cn = i * 16 + ln15;
                float gt = 1.0f / (1.0f + __expf(-(acc[i][r] + gate_b[cn])));
                float ef = __bfloat162float(B[qr * 264 + cn]);   // Ef (read before overwrite)
                float s  = __bfloat162float(rS[cn]);
                float d  = __bfloat162float(rD[cn]);
                B[qr * 264 + cn]       = __float2bfloat16(s + gt * ef);
                B[qr * 264 + 128 + cn] = __float2bfloat16(d + gt * ef);
            }
        }
    }

    // ---- GEMM2: z1 = relu(LN([S'|D']@c1_w + b)) -> B[:,0:128] overlay ----
    {
        f32x4 acc[8] = {};
        bf16x8 fifo[4];
#pragma unroll
        for (int s = 0; s < 4; s++)
            fifo[s] = *(const bf16x8*)(c1_sw + ((size_t)s * 64 + l) * 8);
        bf16x8 acur = *(const bf16x8*)&B[ln15 * 264 + q8];
        bf16x8 anx;
#pragma unroll
        for (int s = 0; s < 64; s++) {
            int kc = s >> 3, i = s & 7;
            if (i == 0 && kc < 7)
                anx = *(const bf16x8*)&B[ln15 * 264 + (kc + 1) * 32 + q8];
            bf16x8 bcur = fifo[s & 3];
            if (s + 4 < 64)
                fifo[s & 3] = *(const bf16x8*)(c1_sw + ((size_t)(s + 4) * 64 + l) * 8);
            acc[i] = __builtin_amdgcn_mfma_f32_16x16x32_bf16(acur, bcur, acc[i], 0, 0, 0);
            if (i == 7) acur = anx;
        }
#pragma unroll
        for (int i = 0; i < 8; i++) {
            float cb = c1_b[i * 16 + ln15];
#pragma unroll
            for (int r = 0; r < 4; r++) acc[i][r] += cb;
        }
        float mean[4], rstd[4];
#pragma unroll
        for (int r = 0; r < 4; r++) {
            float p = 0.0f;
#pragma unroll
            for (int i = 0; i < 8; i++) p += acc[i][r];
            p += __shfl_xor(p, 1, 64); p += __shfl_xor(p, 2, 64);
            p += __shfl_xor(p, 4, 64); p += __shfl_xor(p, 8, 64);
            mean[r] = p * (1.0f / 128.0f);
        }
#pragma unroll
        for (int r = 0; r < 4; r++) {
            float q = 0.0f;
#pragma unroll
            for (int i = 0; i < 8; i++) { float d = acc[i][r] - mean[r]; q += d * d; }
            q += __shfl_xor(q, 1, 64); q += __shfl_xor(q, 2, 64);
            q += __shfl_xor(q, 4, 64); q += __shfl_xor(q, 8, 64);
            rstd[r] = rsqrtf(q * (1.0f / 128.0f) + 1e-5f);
        }
#pragma unroll
        for (int i = 0; i < 8; i++) {
            int cn = i * 16 + ln15;
            float g1 = cl1_g[cn], b1 = cl1_b[cn];
#pragma unroll
            for (int r = 0; r < 4; r++) {
                int qr = quad * 4 + r;
                float y = fmaxf((acc[i][r] - mean[r]) * rstd[r] * g1 + b1, 0.0f);
                B[qr * 264 + cn] = __float2bfloat16(y);
            }
        }
    }

    // ---- GEMM3: z2 = relu(LN(z1@c2_w + b)); out = z2@c3_w + c3_b ----
    {
        f32x4 acc[4] = {};
        bf16x8 fifo[4];
#pragma unroll
        for (int s = 0; s < 4; s++)
            fifo[s] = *(const bf16x8*)(c2_sw + ((size_t)s * 64 + l) * 8);
        bf16x8 acur = *(const bf16x8*)&B[ln15 * 264 + q8];
        bf16x8 anx;
#pragma unroll
        for (int s = 0; s < 16; s++) {
            int kc = s >> 2, i = s & 3;
            if (i == 0 && kc < 3)
                anx = *(const bf16x8*)&B[ln15 * 264 + (kc + 1) * 32 + q8];
            bf16x8 bcur = fifo[s & 3];
            if (s + 4 < 16)
                fifo[s & 3] = *(const bf16x8*)(c2_sw + ((size_t)(s + 4) * 64 + l) * 8);
            acc[i] = __builtin_amdgcn_mfma_f32_16x16x32_bf16(acur, bcur, acc[i], 0, 0, 0);
            if (i == 3) acur = anx;
        }
#pragma unroll
        for (int i = 0; i < 4; i++) {
            float cb = c2_b[i * 16 + ln15];
#pragma unroll
            for (int r = 0; r < 4; r++) acc[i][r] += cb;
        }
        float mean[4], rstd[4];
#pragma unroll
        for (int r = 0; r < 4; r++) {
            float p = 0.0f;
#pragma unroll
            for (int i = 0; i < 4; i++) p += acc[i][r];
            p += __shfl_xor(p, 1, 64); p += __shfl_xor(p, 2, 64);
            p += __shfl_xor(p, 4, 64); p += __shfl_xor(p, 8, 64);
            mean[r] = p * (1.0f / 64.0f);
        }
#pragma unroll
        for (int r = 0; r < 4; r++) {
            float q = 0.0f;
#pragma unroll
            for (int i = 0; i < 4; i++) { float d = acc[i][r] - mean[r]; q += d * d; }
            q += __shfl_xor(q, 1, 64); q += __shfl_xor(q, 2, 64);
            q += __shfl_xor(q, 4, 64); q += __shfl_xor(q, 8, 64);
            rstd[r] = rsqrtf(q * (1.0f / 64.0f) + 1e-5f);
        }
        float w0[4], w1[4];
#pragma unroll
        for (int i = 0; i < 4; i++) {
            float2 cw = *(const float2*)&c3_w[(i * 16 + ln15) * 2];
            w0[i] = cw.x; w1[i] = cw.y;
        }
#pragma unroll
        for (int r = 0; r < 4; r++) {
            float s0 = 0.0f, s1 = 0.0f;
#pragma unroll
            for (int i = 0; i < 4; i++) {
                int cn = i * 16 + ln15;
                float y = fmaxf((acc[i][r] - mean[r]) * rstd[r] * cl2_g[cn] + cl2_b[cn], 0.0f);
                s0 += y * w0[i];
                s1 += y * w1[i];
            }
            s0 += __shfl_xor(s0, 1, 64); s0 += __shfl_xor(s0, 2, 64);
            s0 += __shfl_xor(s0, 4, 64); s0 += __shfl_xor(s0, 8, 64);
            s1 += __shfl_xor(s1, 1, 64); s1 += __shfl_xor(s1, 2, 64);
            s1 += __shfl_xor(s1, 4, 64); s1 += __shfl_xor(s1, 8, 64);
            if (ln15 == 0) {
                int e = e0 + rbase + quad * 4 + r;
                if (e < E) {
                    float2 o; o.x = s0 + c3_b[0]; o.y = s1 + c3_b[1];
                    *(float2*)&out[(size_t)e * 2] = o;
                }
            }
        }
    }
}

extern "C" void kernel_launch(void* const* d_in, const int* in_sizes, int n_in,
                              void* d_out, int out_size, void* d_ws, size_t ws_size,
                              hipStream_t stream) {
    const float* x        = (const float*)d_in[0];
    const int*   eidx     = (const int*)d_in[1];
    const float* eattr    = (const float*)d_in[2];
    const float* ne_w     = (const float*)d_in[3];
    const float* ne_b     = (const float*)d_in[4];
    const float* ne_g     = (const float*)d_in[5];
    const float* ne_beta  = (const float*)d_in[6];
    const float* ee_w     = (const float*)d_in[7];
    const float* ee_b     = (const float*)d_in[8];
    const float* ee_g     = (const float*)d_in[9];
    const float* ee_beta  = (const float*)d_in[10];
    const float* gate_w   = (const float*)d_in[11];
    const float* gate_b   = (const float*)d_in[12];
    const float* gatA_w   = (const float*)d_in[13];
    const float* gatA_as  = (const float*)d_in[14];
    const float* gatA_ad  = (const float*)d_in[15];
    const float* gatA_bias= (const float*)d_in[16];
    const float* gatB_w   = (const float*)d_in[17];
    const float* gatB_as  = (const float*)d_in[18];
    const float* gatB_ad  = (const float*)d_in[19];
    const float* gatB_bias= (const float*)d_in[20];
    const float* ln_g     = (const float*)d_in[21];
    const float* ln_b     = (const float*)d_in[22];
    const float* c1_w     = (const float*)d_in[23];
    const float* c1_b     = (const float*)d_in[24];
    const float* cl1_g    = (const float*)d_in[25];
    const float* cl1_b    = (const float*)d_in[26];
    const float* c2_w     = (const float*)d_in[27];
    const float* c2_b     = (const float*)d_in[28];
    const float* cl2_g    = (const float*)d_in[29];
    const float* cl2_b    = (const float*)d_in[30];
    const float* c3_w     = (const float*)d_in[31];
    const float* c3_b     = (const float*)d_in[32];

    const int N = in_sizes[0] / NFEAT;
    const int E = in_sizes[1] / 2;
    const int E2 = E + N;
    const int* rowp = eidx;
    const int* colp = eidx + E;

    char* ws = (char*)d_ws;
    size_t off = 0;
    auto alloc = [&](size_t bytes) -> void* {
        void* p = ws + off;
        off = (off + bytes + 255) & ~(size_t)255;
        return p;
    };
    int*   deg    = (int*)alloc((size_t)N * 4);
    int*   cursor = (int*)alloc((size_t)N * 4);
    int*   offs   = (int*)alloc((size_t)(N + 1) * 4);
    int*   srcs   = (int*)alloc((size_t)E2 * 4);
    float* a_d    = (float*)alloc((size_t)N * 8 * 4);
    __hip_bfloat16* h_bfA  = (__hip_bfloat16*)alloc((size_t)N * H * 2);
    __hip_bfloat16* h_bfB  = (__hip_bfloat16*)alloc((size_t)N * H * 2);
    __hip_bfloat16* xp_bf  = (__hip_bfloat16*)alloc((size_t)N * XPS * 2);
    __hip_bfloat16* gate_sw= (__hip_bfloat16*)alloc((size_t)49152 * 2);
    __hip_bfloat16* c1_sw  = (__hip_bfloat16*)alloc((size_t)32768 * 2);
    __hip_bfloat16* c2_sw  = (__hip_bfloat16*)alloc((size_t)8192 * 2);
    __hip_bfloat16* wT3    = (__hip_bfloat16*)alloc((size_t)3 * 128 * 128 * 2);
    __hip_bfloat16* ee_sw  = (__hip_bfloat16*)alloc((size_t)4096 * 2);
    (void)ws_size;

    // weight prep
    k_wprep<<<(143360 + 255) / 256, 256, 0, stream>>>(gate_w, c1_w, c2_w, gatA_w, gatB_w, ee_w,
                                                      gate_sw, c1_sw, c2_sw, wT3, ee_sw);

    // CSR build
    hipMemsetAsync(deg, 0, (size_t)N * 4, stream);
    k_degree<<<(E2 + 255) / 256, 256, 0, stream>>>(colp, deg, E, N);
    k_scan<<<1, 1024, 0, stream>>>(deg, offs, cursor, N);
    k_scatter<<<(E2 + 255) / 256, 256, 0, stream>>>(rowp, colp, cursor, srcs, E, N);

    // node encoder -> bf16
    int ngrid = (N + 3) / 4;
    k_node_enc<<<ngrid, 256, 0, stream>>>(x, ne_w, ne_b, ne_g, ne_beta, h_bfA, N);

    int xpgrid = (N + 63) / 64;
    __hip_bfloat16* hin = h_bfA;
    __hip_bfloat16* hout = h_bfB;
    for (int l = 0; l < 2; l++) {
        k_gat_xp_mfma<<<xpgrid, 256, 0, stream>>>(hin, wT3 + (size_t)l * 16384,
                                                  gatA_as + l * H, gatA_ad + l * H,
                                                  xp_bf, a_d, 8, N);
        k_gat_agg<<<ngrid, 256, 0, stream>>>(xp_bf, a_d, offs, srcs,
                                             gatA_bias + l * H, ln_g + l * H, ln_b + l * H,
                                             hout, 8, N);
        __hip_bfloat16* tmp = hin; hin = hout; hout = tmp;
    }
    k_gat_xp_mfma<<<xpgrid, 256, 0, stream>>>(hin, wT3 + (size_t)2 * 16384,
                                              gatB_as, gatB_ad,
                                              xp_bf, a_d, 1, N);
    k_gat_agg<<<ngrid, 256, 0, stream>>>(xp_bf, a_d, offs, srcs,
                                         gatB_bias, ln_g + 2 * H, ln_b + 2 * H,
                                         hout, 1, N);

    // single-pass 4-GEMM MFMA edge classifier (R9 config)
    k_edge_cls_mfma<<<(E + 63) / 64, 256, 0, stream>>>(
        hout, rowp, colp, eattr,
        ee_sw, ee_b, ee_g, ee_beta,
        gate_sw, gate_b,
        c1_sw, c1_b, cl1_g, cl1_b,
        c2_sw, c2_b, cl2_g, cl2_b,
        c3_w, c3_b,
        (float*)d_out, E);
}